// Round 1
// baseline (321.544 us; speedup 1.0000x reference)
//
#include <hip/hip_runtime.h>

// Shapes (fixed per reference): B=2, L=2048, D=1024, H=16, Dh=64
typedef __bf16 bf16;
typedef __attribute__((ext_vector_type(8))) __bf16 bf16x8;
typedef __attribute__((ext_vector_type(4))) __bf16 bf16x4;
typedef __attribute__((ext_vector_type(4))) float f32x4;

__device__ inline bf16 f2bf(float f) {
  unsigned u = __builtin_bit_cast(unsigned, f);
  u += 0x7fff + ((u >> 16) & 1);  // RNE
  unsigned short h = (unsigned short)(u >> 16);
  return __builtin_bit_cast(bf16, h);
}

__device__ inline void gl_lds16(const bf16* g, bf16* l) {
  __builtin_amdgcn_global_load_lds(
      (const __attribute__((address_space(1))) void*)g,
      (__attribute__((address_space(3))) void*)l, 16, 0, 0);
}

// ---------------- fp32 -> bf16 conversion for x and the four W's ----------
__global__ __launch_bounds__(256) void cvt_kernel(
    const float* __restrict__ x, const float* __restrict__ wq,
    const float* __restrict__ wk, const float* __restrict__ wv,
    const float* __restrict__ wo, bf16* __restrict__ dst) {
  int idx = (blockIdx.x * 256 + threadIdx.x) * 4;
  const float* src;
  if (idx < 4194304) {
    src = x + idx;
  } else {
    int j = idx - 4194304;
    int w = j >> 20;  // uniform per block
    const float* sw = (w == 0) ? wq : (w == 1) ? wk : (w == 2) ? wv : wo;
    src = sw + (j & 1048575);
  }
  float4 f = *(const float4*)src;
  bf16x4 o = {f2bf(f.x), f2bf(f.y), f2bf(f.z), f2bf(f.w)};
  *(bf16x4*)(dst + idx) = o;
}

// ---------------- QKV projection GEMM + RoPE epilogue ---------------------
// R11: upgraded 64x64 -> 128x128 m97 structure (16 MFMA : 8 ds_read_b128 :
// 4 gl_lds16 per k-step; acc[4][4] per wave = 64x64 quadrant). Grid 24x32 =
// 768 blocks = 3/CU, matching the ~164-VGPR occupancy of the measured
// 874-TF reference structure. Epilogue keeps the R2 ternary body verbatim
// (if/else or vectorized V stores trigger spills, R7/R8).
__global__ __launch_bounds__(256) void gemm_qkv_kernel(
    const bf16* __restrict__ xb, const bf16* __restrict__ wb,
    const int* __restrict__ pos,
    bf16* __restrict__ Qb, bf16* __restrict__ Kb, bf16* __restrict__ Vtb) {
  __shared__ __align__(16) bf16 As[128 * 32];
  __shared__ __align__(16) bf16 Bs[128 * 32];
  int tid = threadIdx.x;
  int lane = tid & 63, w = tid >> 6;
  int l15 = lane & 15, quad = lane >> 4;
  int mb = blockIdx.y * 128, nb = blockIdx.x * 128;
  int mq = (w & 1) * 64, nq = (w >> 1) * 64;
  const bf16* agp = xb + (size_t)(mb + w * 16 + (lane >> 2)) * 1024 + (lane & 3) * 8;
  const bf16* bgp = wb + (size_t)(nb + w * 16 + (lane >> 2)) * 1024 + (lane & 3) * 8;
  bf16* alp = As + (w * 16) * 32;  // lane writes alp + lane*16B (linear)
  bf16* blp = Bs + (w * 16) * 32;
  f32x4 acc[4][4];
#pragma unroll
  for (int i = 0; i < 4; ++i)
#pragma unroll
    for (int j = 0; j < 4; ++j)
      for (int r = 0; r < 4; ++r) acc[i][j][r] = 0.f;
  for (int kt = 0; kt < 32; ++kt) {
    gl_lds16(agp, alp);
    gl_lds16(agp + 65536, alp + 2048);  // rows +64
    gl_lds16(bgp, blp);
    gl_lds16(bgp + 65536, blp + 2048);
    agp += 32; bgp += 32;
    __syncthreads();
    bf16x8 af[4], bfr[4];
#pragma unroll
    for (int mt = 0; mt < 4; ++mt)
      af[mt] = *(const bf16x8*)(As + (mq + mt * 16 + l15) * 32 + quad * 8);
#pragma unroll
    for (int nt = 0; nt < 4; ++nt)
      bfr[nt] = *(const bf16x8*)(Bs + (nq + nt * 16 + l15) * 32 + quad * 8);
#pragma unroll
    for (int mt = 0; mt < 4; ++mt)
#pragma unroll
      for (int nt = 0; nt < 4; ++nt)
        acc[mt][nt] = __builtin_amdgcn_mfma_f32_16x16x32_bf16(af[mt], bfr[nt], acc[mt][nt], 0, 0, 0);
    __syncthreads();
  }
  // epilogue: C col=l15 (e), row=quad*4+reg (token). RoPE pairs via shfl_xor(1).
#pragma unroll
  for (int nt = 0; nt < 4; ++nt) {
    int e = nb + nq + nt * 16 + l15;  // 0..3071
    bool isv = (e >= 2048);
    int d = e & 63;
    int h = (e & 1023) >> 6;
    float freq = exp2f(-(float)(d & ~1) * 0.20762051f);
#pragma unroll
    for (int mt = 0; mt < 4; ++mt) {
#pragma unroll
      for (int r = 0; r < 4; ++r) {
        int m = mb + mq + mt * 16 + quad * 4 + r;
        int b = m >> 11, ltok = m & 2047;
        float val = acc[mt][nt][r];
        float p = __shfl_xor(val, 1);
        float outv;
        if (!isv) {
          float angle = (float)pos[ltok] * freq;
          float sn, cs;
          sincosf(angle, &sn, &cs);
          outv = (e & 1) ? (p * sn + val * cs) : (val * cs - p * sn);
        } else {
          outv = val;
        }
        bf16 bv = f2bf(outv);
        if (e < 1024) {
          Qb[(((b << 4) + h) * 2048 + ltok) * 64 + d] = bv;
        } else if (!isv) {
          Kb[(((b << 4) + h) * 2048 + ltok) * 64 + d] = bv;
        } else {
          Vtb[(((b << 4) + h) * 64 + d) * 2048 + ltok] = bv;
        }
      }
    }
  }
}

// ---------------- causal flash attention v9 --------------------------------
// R11: K/V per bh = 512 KB; all 32 q-tile blocks of a bh land on the same
// XCD (bh = bidx&31, XCD = bidx%8) -> 4 bh x 512 KB = 2 MB working set per
// 4 MB L2. So LDS staging of L2-resident data was pure overhead (guide
// common-mistake #7). Read K/V fragments direct global->reg (16 B/lane in
// 64 B contiguous segments), delete both per-tile barriers (waves fully
// independent), delete all staging/swizzle code. Only the per-wave pbuf
// round-trip remains (same-wave lgkmcnt ordering, no barrier).
#define SCALE_L2E 0.18033688f  // 0.125 * log2(e)
__global__ __launch_bounds__(256) void attn_kernel(
    const bf16* __restrict__ Qb, const bf16* __restrict__ Kb,
    const bf16* __restrict__ Vtb, bf16* __restrict__ Ob) {
  __shared__ __align__(16) bf16 pbuf[4][16 * 72];
  int tid = threadIdx.x;
  int lane = tid & 63, w = tid >> 6;
  int l15 = lane & 15, quad = lane >> 4;
  int bidx = blockIdx.x;
  int bh = bidx & 31;
  int qt = 31 - (bidx >> 5);  // LPT: longest q-tiles dispatch first
  int qbase = qt * 64;
  const bf16* Qp = Qb + (size_t)bh * 131072;
  const bf16* Kp = Kb + (size_t)bh * 131072;
  const bf16* Vp = Vtb + (size_t)bh * 131072;
  bf16x8 qf[2];
#pragma unroll
  for (int c = 0; c < 2; ++c)
    qf[c] = *(const bf16x8*)(Qp + (size_t)(qbase + w * 16 + l15) * 64 + c * 32 + quad * 8);
  f32x4 oacc[4];
#pragma unroll
  for (int dt = 0; dt < 4; ++dt)
    for (int r = 0; r < 4; ++r) oacc[dt][r] = 0.f;
  float lpart = 0.f;  // per-lane partial denominator
  int qmin_w = qbase + w * 16;
  int ntiles = qt + 1;

  for (int t = 0; t < ntiles; ++t) {
    int kb = t * 64;
    bf16x8 kf[4][2], vf[4][2];
#pragma unroll
    for (int kt = 0; kt < 4; ++kt) {
      const bf16* kr = Kp + (size_t)(kb + kt * 16 + l15) * 64 + quad * 8;
      kf[kt][0] = *(const bf16x8*)(kr);
      kf[kt][1] = *(const bf16x8*)(kr + 32);
    }
#pragma unroll
    for (int dt = 0; dt < 4; ++dt) {
      const bf16* vr = Vp + (size_t)(dt * 16 + l15) * 2048 + kb + quad * 8;
      vf[dt][0] = *(const bf16x8*)(vr);
      vf[dt][1] = *(const bf16x8*)(vr + 32);
    }
    int q = qmin_w + l15;
    f32x4 s[4];
#pragma unroll
    for (int kt = 0; kt < 4; ++kt) {
      for (int r = 0; r < 4; ++r) s[kt][r] = 0.f;
      s[kt] = __builtin_amdgcn_mfma_f32_16x16x32_bf16(kf[kt][0], qf[0], s[kt], 0, 0, 0);
      s[kt] = __builtin_amdgcn_mfma_f32_16x16x32_bf16(kf[kt][1], qf[1], s[kt], 0, 0, 0);
    }
    float pe[16];
    if (kb + 63 > qmin_w) {  // diagonal: per-element mask (wave-uniform test)
#pragma unroll
      for (int kt = 0; kt < 4; ++kt)
#pragma unroll
        for (int r = 0; r < 4; ++r) {
          int key = kb + kt * 16 + quad * 4 + r;
          pe[kt * 4 + r] = (key <= q) ? exp2f(s[kt][r] * SCALE_L2E) : 0.f;
        }
    } else {
#pragma unroll
      for (int kt = 0; kt < 4; ++kt)
#pragma unroll
        for (int r = 0; r < 4; ++r) pe[kt * 4 + r] = exp2f(s[kt][r] * SCALE_L2E);
    }
#pragma unroll
    for (int i = 0; i < 16; ++i) lpart += pe[i];
#pragma unroll
    for (int kt = 0; kt < 4; ++kt) {
      bf16x4 pw = {f2bf(pe[kt * 4]), f2bf(pe[kt * 4 + 1]), f2bf(pe[kt * 4 + 2]), f2bf(pe[kt * 4 + 3])};
      *(bf16x4*)&pbuf[w][l15 * 72 + kt * 16 + quad * 4] = pw;
    }
    // same-wave LDS round-trip: lgkmcnt ordering only, no barrier
    bf16x8 pb0 = *(const bf16x8*)&pbuf[w][l15 * 72 + quad * 8];
    bf16x8 pb1 = *(const bf16x8*)&pbuf[w][l15 * 72 + 32 + quad * 8];
#pragma unroll
    for (int dt = 0; dt < 4; ++dt) {
      oacc[dt] = __builtin_amdgcn_mfma_f32_16x16x32_bf16(vf[dt][0], pb0, oacc[dt], 0, 0, 0);
      oacc[dt] = __builtin_amdgcn_mfma_f32_16x16x32_bf16(vf[dt][1], pb1, oacc[dt], 0, 0, 0);
    }
  }
  float lrun = lpart;
  lrun += __shfl_xor(lrun, 16);
  lrun += __shfl_xor(lrun, 32);
  int b0 = bh >> 4, h = bh & 15;
  float inv = 1.f / lrun;
  int q = qmin_w + l15;
  bf16* obase = Ob + ((size_t)(b0 * 2048 + q)) * 1024 + h * 64;
#pragma unroll
  for (int dt = 0; dt < 4; ++dt)
#pragma unroll
    for (int r = 0; r < 4; ++r)
      obase[dt * 16 + quad * 4 + r] = f2bf(oacc[dt][r] * inv);
}

// ---------------- output projection GEMM (64x64 tile, fp32 out) ------------
// Unchanged from R10 (isolating this round's two changes).
__global__ __launch_bounds__(256) void gemm_out_kernel(
    const bf16* __restrict__ Ob, const bf16* __restrict__ wob,
    float* __restrict__ out) {
  __shared__ __align__(16) bf16 As[64 * 32];
  __shared__ __align__(16) bf16 Bs[64 * 32];
  int tid = threadIdx.x;
  int lane = tid & 63, w = tid >> 6;
  int l15 = lane & 15, quad = lane >> 4;
  int mb = blockIdx.y * 64, nb = blockIdx.x * 64;
  int mq = (w & 1) * 32, nq = (w >> 1) * 32;
  const bf16* agp = Ob + (size_t)(mb + w * 16 + (lane >> 2)) * 1024 + (lane & 3) * 8;
  const bf16* bgp = wob + (size_t)(nb + w * 16 + (lane >> 2)) * 1024 + (lane & 3) * 8;
  bf16* alp = As + (w * 16) * 32;
  bf16* blp = Bs + (w * 16) * 32;
  f32x4 acc[2][2];
#pragma unroll
  for (int i = 0; i < 2; ++i)
#pragma unroll
    for (int j = 0; j < 2; ++j)
      for (int r = 0; r < 4; ++r) acc[i][j][r] = 0.f;
  for (int kt = 0; kt < 32; ++kt) {
    gl_lds16(agp, alp);
    gl_lds16(bgp, blp);
    agp += 32; bgp += 32;
    __syncthreads();
    bf16x8 af[2], bfr[2];
#pragma unroll
    for (int mt = 0; mt < 2; ++mt)
      af[mt] = *(const bf16x8*)(As + (mq + mt * 16 + l15) * 32 + quad * 8);
#pragma unroll
    for (int nt = 0; nt < 2; ++nt)
      bfr[nt] = *(const bf16x8*)(Bs + (nq + nt * 16 + l15) * 32 + quad * 8);
#pragma unroll
    for (int mt = 0; mt < 2; ++mt)
#pragma unroll
      for (int nt = 0; nt < 2; ++nt)
        acc[mt][nt] = __builtin_amdgcn_mfma_f32_16x16x32_bf16(af[mt], bfr[nt], acc[mt][nt], 0, 0, 0);
    __syncthreads();
  }
#pragma unroll
  for (int mt = 0; mt < 2; ++mt)
#pragma unroll
    for (int nt = 0; nt < 2; ++nt)
#pragma unroll
      for (int r = 0; r < 4; ++r)
        out[(size_t)(mb + mq + mt * 16 + quad * 4 + r) * 1024 + nb + nq + nt * 16 + l15] = acc[mt][nt][r];
}

extern "C" void kernel_launch(void* const* d_in, const int* in_sizes, int n_in,
                              void* d_out, int out_size, void* d_ws, size_t ws_size,
                              hipStream_t stream) {
  const float* x  = (const float*)d_in[0];
  const float* wq = (const float*)d_in[1];
  const float* wk = (const float*)d_in[2];
  const float* wv = (const float*)d_in[3];
  const float* wo = (const float*)d_in[4];
  const int* pos  = (const int*)d_in[5];
  float* out = (float*)d_out;
  // ws layout (bf16 elems): xb[4M] | wb[4x1M] | Q[4M] | K[4M] | Vt[4M] | O[4M]
  bf16* wsb = (bf16*)d_ws;
  bf16* xb  = wsb;
  bf16* wb  = wsb + 4194304;
  bf16* Qb  = wsb + 8388608;
  bf16* Kb  = wsb + 12582912;
  bf16* Vtb = wsb + 16777216;
  bf16* Obf = wsb + 20971520;
  hipLaunchKernelGGL(cvt_kernel, dim3(8192), dim3(256), 0, stream, x, wq, wk, wv, wo, wsb);
  hipLaunchKernelGGL(gemm_qkv_kernel, dim3(24, 32), dim3(256), 0, stream, xb, wb, pos, Qb, Kb, Vtb);
  hipLaunchKernelGGL(attn_kernel, dim3(1024), dim3(256), 0, stream, Qb, Kb, Vtb, Obf);
  hipLaunchKernelGGL(gemm_out_kernel, dim3(16, 64), dim3(256), 0, stream, Obf, wb + 3 * 1048576, out);
}

// Round 3
// 299.971 us; speedup vs baseline: 1.0719x; 1.0719x over previous
//
#include <hip/hip_runtime.h>

// Shapes (fixed per reference): B=2, L=2048, D=1024, H=16, Dh=64
typedef __bf16 bf16;
typedef __attribute__((ext_vector_type(8))) __bf16 bf16x8;
typedef __attribute__((ext_vector_type(4))) __bf16 bf16x4;
typedef __attribute__((ext_vector_type(4))) float f32x4;

__device__ inline bf16 f2bf(float f) {
  unsigned u = __builtin_bit_cast(unsigned, f);
  u += 0x7fff + ((u >> 16) & 1);  // RNE
  unsigned short h = (unsigned short)(u >> 16);
  return __builtin_bit_cast(bf16, h);
}

__device__ inline void gl_lds16(const bf16* g, bf16* l) {
  __builtin_amdgcn_global_load_lds(
      (const __attribute__((address_space(1))) void*)g,
      (__attribute__((address_space(3))) void*)l, 16, 0, 0);
}

// ---------------- fp32 -> bf16 conversion for x and the four W's ----------
__global__ __launch_bounds__(256) void cvt_kernel(
    const float* __restrict__ x, const float* __restrict__ wq,
    const float* __restrict__ wk, const float* __restrict__ wv,
    const float* __restrict__ wo, bf16* __restrict__ dst) {
  int idx = (blockIdx.x * 256 + threadIdx.x) * 4;
  const float* src;
  if (idx < 4194304) {
    src = x + idx;
  } else {
    int j = idx - 4194304;
    int w = j >> 20;  // uniform per block
    const float* sw = (w == 0) ? wq : (w == 1) ? wk : (w == 2) ? wv : wo;
    src = sw + (j & 1048575);
  }
  float4 f = *(const float4*)src;
  bf16x4 o = {f2bf(f.x), f2bf(f.y), f2bf(f.z), f2bf(f.w)};
  *(bf16x4*)(dst + idx) = o;
}

// ---------------- QKV projection GEMM + RoPE epilogue ---------------------
// R12: reverted verbatim to the proven R10 64x64 structure. The R11 128x128
// upgrade (acc[4][4] = 64 VGPR) collided with the RoPE epilogue's register
// pressure (sincosf temps + shfl + scattered stores) and spilled: dispatch
// ~60 -> ~158 us. 64x64 tile, grid 3072 -> 8 blocks/CU; acc[2][2] ~56 VGPR.
__global__ __launch_bounds__(256) void gemm_qkv_kernel(
    const bf16* __restrict__ xb, const bf16* __restrict__ wb,
    const int* __restrict__ pos,
    bf16* __restrict__ Qb, bf16* __restrict__ Kb, bf16* __restrict__ Vtb) {
  __shared__ __align__(16) bf16 As[64 * 32];
  __shared__ __align__(16) bf16 Bs[64 * 32];
  int tid = threadIdx.x;
  int lane = tid & 63, w = tid >> 6;
  int l15 = lane & 15, quad = lane >> 4;
  int mb = blockIdx.y * 64, nb = blockIdx.x * 64;
  int mq = (w & 1) * 32, nq = (w >> 1) * 32;
  const bf16* agp = xb + (size_t)(mb + w * 16 + (lane >> 2)) * 1024 + (lane & 3) * 8;
  const bf16* bgp = wb + (size_t)(nb + w * 16 + (lane >> 2)) * 1024 + (lane & 3) * 8;
  bf16* alp = As + (w * 16) * 32;
  bf16* blp = Bs + (w * 16) * 32;
  f32x4 acc[2][2];
#pragma unroll
  for (int i = 0; i < 2; ++i)
#pragma unroll
    for (int j = 0; j < 2; ++j)
      for (int r = 0; r < 4; ++r) acc[i][j][r] = 0.f;
  for (int kt = 0; kt < 32; ++kt) {
    gl_lds16(agp, alp);
    gl_lds16(bgp, blp);
    agp += 32; bgp += 32;
    __syncthreads();
    bf16x8 af[2], bfr[2];
#pragma unroll
    for (int mt = 0; mt < 2; ++mt)
      af[mt] = *(const bf16x8*)(As + (mq + mt * 16 + l15) * 32 + quad * 8);
#pragma unroll
    for (int nt = 0; nt < 2; ++nt)
      bfr[nt] = *(const bf16x8*)(Bs + (nq + nt * 16 + l15) * 32 + quad * 8);
#pragma unroll
    for (int mt = 0; mt < 2; ++mt)
#pragma unroll
      for (int nt = 0; nt < 2; ++nt)
        acc[mt][nt] = __builtin_amdgcn_mfma_f32_16x16x32_bf16(af[mt], bfr[nt], acc[mt][nt], 0, 0, 0);
    __syncthreads();
  }
  // epilogue: C col=l15 (e), row=quad*4+reg (token). RoPE pairs via shfl_xor(1).
#pragma unroll
  for (int nt = 0; nt < 2; ++nt) {
    int e = nb + nq + nt * 16 + l15;  // 0..3071
    bool isv = (e >= 2048);
    int d = e & 63;
    int h = (e & 1023) >> 6;
    float freq = exp2f(-(float)(d & ~1) * 0.20762051f);
#pragma unroll
    for (int mt = 0; mt < 2; ++mt) {
#pragma unroll
      for (int r = 0; r < 4; ++r) {
        int m = mb + mq + mt * 16 + quad * 4 + r;
        int b = m >> 11, ltok = m & 2047;
        float val = acc[mt][nt][r];
        float p = __shfl_xor(val, 1);
        float outv;
        if (!isv) {
          float angle = (float)pos[ltok] * freq;
          float sn, cs;
          sincosf(angle, &sn, &cs);
          outv = (e & 1) ? (p * sn + val * cs) : (val * cs - p * sn);
        } else {
          outv = val;
        }
        bf16 bv = f2bf(outv);
        if (e < 1024) {
          Qb[(((b << 4) + h) * 2048 + ltok) * 64 + d] = bv;
        } else if (!isv) {
          Kb[(((b << 4) + h) * 2048 + ltok) * 64 + d] = bv;
        } else {
          Vtb[(((b << 4) + h) * 64 + d) * 2048 + ltok] = bv;
        }
      }
    }
  }
}

// ---------------- causal flash attention v10 -------------------------------
// R12: R11's direct-from-L2 reads were right on traffic (FETCH 12.3 MB, L2
// absorbed everything) but latency-bound (MfmaUtil 5%, VGPR=68 -> compiler
// sank loads next to uses, zero ILP). Fix: static software pipeline.
//   - K for tile t+1 prefetched into alternate named regs (kfA/kfB swap via
//     two-phase unroll; all indices compile-time, rule #20 safe).
//   - V for tile t issued at tile start; first use is after QK (8 MFMA) +
//     mask + 16 exp2 (~300+ cyc) -> covers ~200 cyc L2 latency without a
//     second V buffer (keeps VGPR ~150, occupancy uncapped).
#define SCALE_L2E 0.18033688f  // 0.125 * log2(e)
__global__ __launch_bounds__(256) void attn_kernel(
    const bf16* __restrict__ Qb, const bf16* __restrict__ Kb,
    const bf16* __restrict__ Vtb, bf16* __restrict__ Ob) {
  __shared__ __align__(16) bf16 pbuf[4][16 * 72];
  int tid = threadIdx.x;
  int lane = tid & 63, w = tid >> 6;
  int l15 = lane & 15, quad = lane >> 4;
  int bidx = blockIdx.x;
  int bh = bidx & 31;
  int qt = 31 - (bidx >> 5);  // LPT: longest q-tiles dispatch first
  int qbase = qt * 64;
  const bf16* Qp = Qb + (size_t)bh * 131072;
  const bf16* Kp = Kb + (size_t)bh * 131072;
  const bf16* Vp = Vtb + (size_t)bh * 131072;
  bf16x8 qf[2];
#pragma unroll
  for (int c = 0; c < 2; ++c)
    qf[c] = *(const bf16x8*)(Qp + (size_t)(qbase + w * 16 + l15) * 64 + c * 32 + quad * 8);
  f32x4 oacc[4];
#pragma unroll
  for (int dt = 0; dt < 4; ++dt)
    for (int r = 0; r < 4; ++r) oacc[dt][r] = 0.f;
  float lpart = 0.f;  // per-lane partial denominator
  int qmin_w = qbase + w * 16;
  int ntiles = qt + 1;

  bf16x8 kfA[4][2], kfB[4][2], vf[4][2];
  // prologue: load K tile 0
#pragma unroll
  for (int kt = 0; kt < 4; ++kt) {
    const bf16* kr = Kp + (size_t)(kt * 16 + l15) * 64 + quad * 8;
    kfA[kt][0] = *(const bf16x8*)(kr);
    kfA[kt][1] = *(const bf16x8*)(kr + 32);
  }

#define ATTN_STEP(KFC, KFN)                                                   \
  {                                                                           \
    int kb = t * 64;                                                          \
    /* issue V(t) now; first use is after QK+softmax (~300 cyc) */            \
    _Pragma("unroll") for (int dt = 0; dt < 4; ++dt) {                        \
      const bf16* vr = Vp + (size_t)(dt * 16 + l15) * 2048 + kb + quad * 8;   \
      vf[dt][0] = *(const bf16x8*)(vr);                                       \
      vf[dt][1] = *(const bf16x8*)(vr + 32);                                  \
    }                                                                         \
    /* prefetch K(t+1) into the alternate buffer */                           \
    if (t + 1 < ntiles) {                                                     \
      _Pragma("unroll") for (int kt = 0; kt < 4; ++kt) {                      \
        const bf16* kr = Kp + (size_t)(kb + 64 + kt * 16 + l15) * 64 + quad * 8; \
        KFN[kt][0] = *(const bf16x8*)(kr);                                    \
        KFN[kt][1] = *(const bf16x8*)(kr + 32);                               \
      }                                                                       \
    }                                                                         \
    int q = qmin_w + l15;                                                     \
    f32x4 s[4];                                                               \
    _Pragma("unroll") for (int kt = 0; kt < 4; ++kt) {                        \
      for (int r = 0; r < 4; ++r) s[kt][r] = 0.f;                             \
      s[kt] = __builtin_amdgcn_mfma_f32_16x16x32_bf16(KFC[kt][0], qf[0], s[kt], 0, 0, 0); \
      s[kt] = __builtin_amdgcn_mfma_f32_16x16x32_bf16(KFC[kt][1], qf[1], s[kt], 0, 0, 0); \
    }                                                                         \
    float pe[16];                                                             \
    if (kb + 63 > qmin_w) { /* diagonal: per-element mask */                  \
      _Pragma("unroll") for (int kt = 0; kt < 4; ++kt)                        \
          _Pragma("unroll") for (int r = 0; r < 4; ++r) {                     \
        int key = kb + kt * 16 + quad * 4 + r;                                \
        pe[kt * 4 + r] = (key <= q) ? exp2f(s[kt][r] * SCALE_L2E) : 0.f;      \
      }                                                                       \
    } else {                                                                  \
      _Pragma("unroll") for (int kt = 0; kt < 4; ++kt)                        \
          _Pragma("unroll") for (int r = 0; r < 4; ++r)                       \
              pe[kt * 4 + r] = exp2f(s[kt][r] * SCALE_L2E);                   \
    }                                                                         \
    _Pragma("unroll") for (int i = 0; i < 16; ++i) lpart += pe[i];            \
    _Pragma("unroll") for (int kt = 0; kt < 4; ++kt) {                        \
      bf16x4 pw = {f2bf(pe[kt * 4]), f2bf(pe[kt * 4 + 1]),                    \
                   f2bf(pe[kt * 4 + 2]), f2bf(pe[kt * 4 + 3])};               \
      *(bf16x4*)&pbuf[w][l15 * 72 + kt * 16 + quad * 4] = pw;                 \
    }                                                                         \
    /* same-wave LDS round-trip: lgkmcnt ordering only, no barrier */         \
    bf16x8 pb0 = *(const bf16x8*)&pbuf[w][l15 * 72 + quad * 8];               \
    bf16x8 pb1 = *(const bf16x8*)&pbuf[w][l15 * 72 + 32 + quad * 8];          \
    _Pragma("unroll") for (int dt = 0; dt < 4; ++dt) {                        \
      oacc[dt] = __builtin_amdgcn_mfma_f32_16x16x32_bf16(vf[dt][0], pb0, oacc[dt], 0, 0, 0); \
      oacc[dt] = __builtin_amdgcn_mfma_f32_16x16x32_bf16(vf[dt][1], pb1, oacc[dt], 0, 0, 0); \
    }                                                                         \
  }

  int t = 0;
  for (;;) {
    ATTN_STEP(kfA, kfB);
    ++t;
    if (t >= ntiles) break;
    ATTN_STEP(kfB, kfA);
    ++t;
    if (t >= ntiles) break;
  }
#undef ATTN_STEP

  float lrun = lpart;
  lrun += __shfl_xor(lrun, 16);
  lrun += __shfl_xor(lrun, 32);
  int b0 = bh >> 4, h = bh & 15;
  float inv = 1.f / lrun;
  int q = qmin_w + l15;
  bf16* obase = Ob + ((size_t)(b0 * 2048 + q)) * 1024 + h * 64;
#pragma unroll
  for (int dt = 0; dt < 4; ++dt)
#pragma unroll
    for (int r = 0; r < 4; ++r)
      obase[dt * 16 + quad * 4 + r] = f2bf(oacc[dt][r] * inv);
}

// ---------------- output projection GEMM (64x64 tile, fp32 out) ------------
__global__ __launch_bounds__(256) void gemm_out_kernel(
    const bf16* __restrict__ Ob, const bf16* __restrict__ wob,
    float* __restrict__ out) {
  __shared__ __align__(16) bf16 As[64 * 32];
  __shared__ __align__(16) bf16 Bs[64 * 32];
  int tid = threadIdx.x;
  int lane = tid & 63, w = tid >> 6;
  int l15 = lane & 15, quad = lane >> 4;
  int mb = blockIdx.y * 64, nb = blockIdx.x * 64;
  int mq = (w & 1) * 32, nq = (w >> 1) * 32;
  const bf16* agp = Ob + (size_t)(mb + w * 16 + (lane >> 2)) * 1024 + (lane & 3) * 8;
  const bf16* bgp = wob + (size_t)(nb + w * 16 + (lane >> 2)) * 1024 + (lane & 3) * 8;
  bf16* alp = As + (w * 16) * 32;
  bf16* blp = Bs + (w * 16) * 32;
  f32x4 acc[2][2];
#pragma unroll
  for (int i = 0; i < 2; ++i)
#pragma unroll
    for (int j = 0; j < 2; ++j)
      for (int r = 0; r < 4; ++r) acc[i][j][r] = 0.f;
  for (int kt = 0; kt < 32; ++kt) {
    gl_lds16(agp, alp);
    gl_lds16(bgp, blp);
    agp += 32; bgp += 32;
    __syncthreads();
    bf16x8 af[2], bfr[2];
#pragma unroll
    for (int mt = 0; mt < 2; ++mt)
      af[mt] = *(const bf16x8*)(As + (mq + mt * 16 + l15) * 32 + quad * 8);
#pragma unroll
    for (int nt = 0; nt < 2; ++nt)
      bfr[nt] = *(const bf16x8*)(Bs + (nq + nt * 16 + l15) * 32 + quad * 8);
#pragma unroll
    for (int mt = 0; mt < 2; ++mt)
#pragma unroll
      for (int nt = 0; nt < 2; ++nt)
        acc[mt][nt] = __builtin_amdgcn_mfma_f32_16x16x32_bf16(af[mt], bfr[nt], acc[mt][nt], 0, 0, 0);
    __syncthreads();
  }
#pragma unroll
  for (int mt = 0; mt < 2; ++mt)
#pragma unroll
    for (int nt = 0; nt < 2; ++nt)
#pragma unroll
      for (int r = 0; r < 4; ++r)
        out[(size_t)(mb + mq + mt * 16 + quad * 4 + r) * 1024 + nb + nq + nt * 16 + l15] = acc[mt][nt][r];
}

extern "C" void kernel_launch(void* const* d_in, const int* in_sizes, int n_in,
                              void* d_out, int out_size, void* d_ws, size_t ws_size,
                              hipStream_t stream) {
  const float* x  = (const float*)d_in[0];
  const float* wq = (const float*)d_in[1];
  const float* wk = (const float*)d_in[2];
  const float* wv = (const float*)d_in[3];
  const float* wo = (const float*)d_in[4];
  const int* pos  = (const int*)d_in[5];
  float* out = (float*)d_out;
  // ws layout (bf16 elems): xb[4M] | wb[4x1M] | Q[4M] | K[4M] | Vt[4M] | O[4M]
  bf16* wsb = (bf16*)d_ws;
  bf16* xb  = wsb;
  bf16* wb  = wsb + 4194304;
  bf16* Qb  = wsb + 8388608;
  bf16* Kb  = wsb + 12582912;
  bf16* Vtb = wsb + 16777216;
  bf16* Obf = wsb + 20971520;
  hipLaunchKernelGGL(cvt_kernel, dim3(8192), dim3(256), 0, stream, x, wq, wk, wv, wo, wsb);
  hipLaunchKernelGGL(gemm_qkv_kernel, dim3(48, 64), dim3(256), 0, stream, xb, wb, pos, Qb, Kb, Vtb);
  hipLaunchKernelGGL(attn_kernel, dim3(1024), dim3(256), 0, stream, Qb, Kb, Vtb, Obf);
  hipLaunchKernelGGL(gemm_out_kernel, dim3(16, 64), dim3(256), 0, stream, Obf, wb + 3 * 1048576, out);
}

// Round 4
// 227.504 us; speedup vs baseline: 1.4134x; 1.3185x over previous
//
#include <hip/hip_runtime.h>

// Shapes (fixed per reference): B=2, L=2048, D=1024, H=16, Dh=64
typedef __bf16 bf16;
typedef __attribute__((ext_vector_type(8))) __bf16 bf16x8;
typedef __attribute__((ext_vector_type(4))) __bf16 bf16x4;
typedef __attribute__((ext_vector_type(4))) float f32x4;

__device__ inline bf16 f2bf(float f) {
  unsigned u = __builtin_bit_cast(unsigned, f);
  u += 0x7fff + ((u >> 16) & 1);  // RNE
  unsigned short h = (unsigned short)(u >> 16);
  return __builtin_bit_cast(bf16, h);
}

__device__ inline void gl_lds16(const bf16* g, bf16* l) {
  __builtin_amdgcn_global_load_lds(
      (const __attribute__((address_space(1))) void*)g,
      (__attribute__((address_space(3))) void*)l, 16, 0, 0);
}

// ---------------- fp32 -> bf16 conversion for x and the four W's ----------
__global__ __launch_bounds__(256) void cvt_kernel(
    const float* __restrict__ x, const float* __restrict__ wq,
    const float* __restrict__ wk, const float* __restrict__ wv,
    const float* __restrict__ wo, bf16* __restrict__ dst) {
  int idx = (blockIdx.x * 256 + threadIdx.x) * 4;
  const float* src;
  if (idx < 4194304) {
    src = x + idx;
  } else {
    int j = idx - 4194304;
    int w = j >> 20;  // uniform per block
    const float* sw = (w == 0) ? wq : (w == 1) ? wk : (w == 2) ? wv : wo;
    src = sw + (j & 1048575);
  }
  float4 f = *(const float4*)src;
  bf16x4 o = {f2bf(f.x), f2bf(f.y), f2bf(f.z), f2bf(f.w)};
  *(bf16x4*)(dst + idx) = o;
}

// ---------------- RoPE cos/sin table: tab[tok*64 + j*2] = {cos, sin} ------
// 2048 toks x 32 freqs x float2 = 512 KB, L2-resident during gemm_qkv.
// Lives in the (dead until attn) Obf workspace region -> zero extra ws.
__global__ __launch_bounds__(256) void rope_tab_kernel(
    const int* __restrict__ pos, float* __restrict__ tab) {
  int gid = blockIdx.x * 256 + threadIdx.x;  // 65536 items
  int tok = gid >> 5, j = gid & 31;
  float freq = exp2f(-(float)(2 * j) * 0.20762051f);
  float angle = (float)pos[tok] * freq;
  float sn, cs;
  sincosf(angle, &sn, &cs);
  *(float2*)(tab + tok * 64 + j * 2) = make_float2(cs, sn);
}

// ---------------- QKV projection GEMM + RoPE epilogue ---------------------
// R13: 128x128 m97-class structure (16 MFMA : 8 ds_read_b128 : 4 gl_lds16
// per k-step, acc[4][4]/wave). R11's 128^2 attempt regressed because its
// epilogue ran 64 sincosf LIBM CALLS per thread (4x the 64^2 count, plus
// call-clobber register pressure). Fixed by table lookup: one 8 B
// L2-resident load replaces each sincosf -> no calls, no spill pressure.
// Grid 24x32 = 768 blocks = 3/CU.
__global__ __launch_bounds__(256) void gemm_qkv_kernel(
    const bf16* __restrict__ xb, const bf16* __restrict__ wb,
    const float* __restrict__ tab,
    bf16* __restrict__ Qb, bf16* __restrict__ Kb, bf16* __restrict__ Vtb) {
  __shared__ __align__(16) bf16 As[128 * 32];
  __shared__ __align__(16) bf16 Bs[128 * 32];
  int tid = threadIdx.x;
  int lane = tid & 63, w = tid >> 6;
  int l15 = lane & 15, quad = lane >> 4;
  int mb = blockIdx.y * 128, nb = blockIdx.x * 128;
  int mq = (w & 1) * 64, nq = (w >> 1) * 64;
  const bf16* agp = xb + (size_t)(mb + w * 16 + (lane >> 2)) * 1024 + (lane & 3) * 8;
  const bf16* bgp = wb + (size_t)(nb + w * 16 + (lane >> 2)) * 1024 + (lane & 3) * 8;
  bf16* alp = As + (w * 16) * 32;  // lane writes alp + lane*16B (linear)
  bf16* blp = Bs + (w * 16) * 32;
  f32x4 acc[4][4];
#pragma unroll
  for (int i = 0; i < 4; ++i)
#pragma unroll
    for (int j = 0; j < 4; ++j)
      for (int r = 0; r < 4; ++r) acc[i][j][r] = 0.f;
  for (int kt = 0; kt < 32; ++kt) {
    gl_lds16(agp, alp);
    gl_lds16(agp + 65536, alp + 2048);  // rows +64
    gl_lds16(bgp, blp);
    gl_lds16(bgp + 65536, blp + 2048);
    agp += 32; bgp += 32;
    __syncthreads();
    bf16x8 af[4], bfr[4];
#pragma unroll
    for (int mt = 0; mt < 4; ++mt)
      af[mt] = *(const bf16x8*)(As + (mq + mt * 16 + l15) * 32 + quad * 8);
#pragma unroll
    for (int nt = 0; nt < 4; ++nt)
      bfr[nt] = *(const bf16x8*)(Bs + (nq + nt * 16 + l15) * 32 + quad * 8);
#pragma unroll
    for (int mt = 0; mt < 4; ++mt)
#pragma unroll
      for (int nt = 0; nt < 4; ++nt)
        acc[mt][nt] = __builtin_amdgcn_mfma_f32_16x16x32_bf16(af[mt], bfr[nt], acc[mt][nt], 0, 0, 0);
    __syncthreads();
  }
  // epilogue: C col=l15 (e), row=quad*4+reg (token). RoPE pairs via shfl_xor(1).
#pragma unroll
  for (int nt = 0; nt < 4; ++nt) {
    int e = nb + nq + nt * 16 + l15;  // 0..3071
    bool isv = (e >= 2048);
    int d = e & 63;
    int h = (e & 1023) >> 6;
    int tbase = d & ~1;  // table column: 2*(d>>1)
#pragma unroll
    for (int mt = 0; mt < 4; ++mt) {
#pragma unroll
      for (int r = 0; r < 4; ++r) {
        int m = mb + mq + mt * 16 + quad * 4 + r;
        int b = m >> 11, ltok = m & 2047;
        float val = acc[mt][nt][r];
        float p = __shfl_xor(val, 1);
        float outv;
        if (!isv) {
          float2 cs2 = *(const float2*)(tab + ltok * 64 + tbase);
          outv = (e & 1) ? (p * cs2.y + val * cs2.x) : (val * cs2.x - p * cs2.y);
        } else {
          outv = val;
        }
        bf16 bv = f2bf(outv);
        if (e < 1024) {
          Qb[(((b << 4) + h) * 2048 + ltok) * 64 + d] = bv;
        } else if (!isv) {
          Kb[(((b << 4) + h) * 2048 + ltok) * 64 + d] = bv;
        } else {
          Vtb[(((b << 4) + h) * 64 + d) * 2048 + ltok] = bv;
        }
      }
    }
  }
}

// ---------------- causal flash attention v8 (R10 verbatim) -----------------
// R13: restored. LDS staging is the point: 4 waves share one staged K/V copy
// -> per-XCD L2 traffic ~35 MB vs ~138 MB for per-wave direct reads (all 32
// q-blocks of a bh sit on one XCD). R11/R12's direct-read variants measured
// 135/136 us; this structure was ~50 us in the 212.9 us session.
#define SCALE_L2E 0.18033688f  // 0.125 * log2(e)
__global__ __launch_bounds__(256) void attn_kernel(
    const bf16* __restrict__ Qb, const bf16* __restrict__ Kb,
    const bf16* __restrict__ Vtb, bf16* __restrict__ Ob) {
  __shared__ __align__(16) bf16 Ks[64 * 64];
  __shared__ __align__(16) bf16 Vs[64 * 64];
  __shared__ __align__(16) bf16 pbuf[4][16 * 72];
  int tid = threadIdx.x;
  int lane = tid & 63, w = tid >> 6;
  int l15 = lane & 15, quad = lane >> 4;
  int bidx = blockIdx.x;
  int bh = bidx & 31;
  int qt = 31 - (bidx >> 5);  // LPT: longest q-tiles dispatch first
  int qbase = qt * 64;
  const bf16* Qp = Qb + (size_t)bh * 131072;
  const bf16* Kp = Kb + (size_t)bh * 131072;
  const bf16* Vp = Vtb + (size_t)bh * 131072;
  int r8 = lane >> 3;
  int gsw8 = (lane & 7) ^ r8;       // staging source granule swizzle
  int g0 = quad ^ (l15 & 7);        // read granule, k-chunk 0
  int g1 = (4 + quad) ^ (l15 & 7);  // read granule, k-chunk 1
  bf16x8 qf[2];
#pragma unroll
  for (int c = 0; c < 2; ++c)
    qf[c] = *(const bf16x8*)(Qp + (size_t)(qbase + w * 16 + l15) * 64 + c * 32 + quad * 8);
  f32x4 oacc[4];
#pragma unroll
  for (int dt = 0; dt < 4; ++dt)
    for (int r = 0; r < 4; ++r) oacc[dt][r] = 0.f;
  float lpart = 0.f;  // per-lane partial denominator
  int qmin_w = qbase + w * 16;
  int qmax_w = qmin_w + 15;
  int ntiles = qt + 1;

  for (int t = 0; t < ntiles; ++t) {
    int kb = t * 64;
    {  // stage tile t (single buffer): wave w covers rows [w*16, w*16+16)
      const bf16* ksrc = Kp + (size_t)(kb + w * 16 + r8) * 64 + gsw8 * 8;
      bf16* kdst = &Ks[(w * 16) * 64];
      gl_lds16(ksrc, kdst);
      gl_lds16(ksrc + 8 * 64, kdst + 8 * 64);
      const bf16* vsrc = Vp + (size_t)(w * 16 + r8) * 2048 + kb + gsw8 * 8;
      bf16* vdst = &Vs[(w * 16) * 64];
      gl_lds16(vsrc, vdst);
      gl_lds16(vsrc + 8 * 2048, vdst + 8 * 64);
    }
    __syncthreads();  // DMA drained
    if (kb <= qmax_w) {  // wave-uniform: skip compute on fully-masked tiles
      bf16x8 kf[4][2], vf[4][2];
#pragma unroll
      for (int kt = 0; kt < 4; ++kt) {
        kf[kt][0] = *(const bf16x8*)(&Ks[(kt * 16 + l15) * 64 + g0 * 8]);
        kf[kt][1] = *(const bf16x8*)(&Ks[(kt * 16 + l15) * 64 + g1 * 8]);
      }
#pragma unroll
      for (int dt = 0; dt < 4; ++dt) {
        vf[dt][0] = *(const bf16x8*)(&Vs[(dt * 16 + l15) * 64 + g0 * 8]);
        vf[dt][1] = *(const bf16x8*)(&Vs[(dt * 16 + l15) * 64 + g1 * 8]);
      }
      int q = qmin_w + l15;
      f32x4 s[4];
#pragma unroll
      for (int kt = 0; kt < 4; ++kt) {
        for (int r = 0; r < 4; ++r) s[kt][r] = 0.f;
        s[kt] = __builtin_amdgcn_mfma_f32_16x16x32_bf16(kf[kt][0], qf[0], s[kt], 0, 0, 0);
        s[kt] = __builtin_amdgcn_mfma_f32_16x16x32_bf16(kf[kt][1], qf[1], s[kt], 0, 0, 0);
      }
      float pe[16];
      if (kb + 63 > qmin_w) {  // diagonal: per-element mask (wave-uniform test)
#pragma unroll
        for (int kt = 0; kt < 4; ++kt)
#pragma unroll
          for (int r = 0; r < 4; ++r) {
            int key = kb + kt * 16 + quad * 4 + r;
            pe[kt * 4 + r] = (key <= q) ? exp2f(s[kt][r] * SCALE_L2E) : 0.f;
          }
      } else {
#pragma unroll
        for (int kt = 0; kt < 4; ++kt)
#pragma unroll
          for (int r = 0; r < 4; ++r) pe[kt * 4 + r] = exp2f(s[kt][r] * SCALE_L2E);
      }
#pragma unroll
      for (int i = 0; i < 16; ++i) lpart += pe[i];
#pragma unroll
      for (int kt = 0; kt < 4; ++kt) {
        bf16x4 pw = {f2bf(pe[kt * 4]), f2bf(pe[kt * 4 + 1]), f2bf(pe[kt * 4 + 2]), f2bf(pe[kt * 4 + 3])};
        *(bf16x4*)&pbuf[w][l15 * 72 + kt * 16 + quad * 4] = pw;
      }
      // same-wave LDS round-trip: lgkmcnt ordering only, no barrier
      bf16x8 pb0 = *(const bf16x8*)&pbuf[w][l15 * 72 + quad * 8];
      bf16x8 pb1 = *(const bf16x8*)&pbuf[w][l15 * 72 + 32 + quad * 8];
#pragma unroll
      for (int dt = 0; dt < 4; ++dt) {
        oacc[dt] = __builtin_amdgcn_mfma_f32_16x16x32_bf16(vf[dt][0], pb0, oacc[dt], 0, 0, 0);
        oacc[dt] = __builtin_amdgcn_mfma_f32_16x16x32_bf16(vf[dt][1], pb1, oacc[dt], 0, 0, 0);
      }
    }
    __syncthreads();  // all reads of Ks/Vs done before next stage
  }
  float lrun = lpart;
  lrun += __shfl_xor(lrun, 16);
  lrun += __shfl_xor(lrun, 32);
  int b0 = bh >> 4, h = bh & 15;
  float inv = 1.f / lrun;
  int q = qmin_w + l15;
  bf16* obase = Ob + ((size_t)(b0 * 2048 + q)) * 1024 + h * 64;
#pragma unroll
  for (int dt = 0; dt < 4; ++dt)
#pragma unroll
    for (int r = 0; r < 4; ++r)
      obase[dt * 16 + quad * 4 + r] = f2bf(oacc[dt][r] * inv);
}

// ---------------- output projection GEMM (64x64 tile, fp32 out) ------------
__global__ __launch_bounds__(256) void gemm_out_kernel(
    const bf16* __restrict__ Ob, const bf16* __restrict__ wob,
    float* __restrict__ out) {
  __shared__ __align__(16) bf16 As[64 * 32];
  __shared__ __align__(16) bf16 Bs[64 * 32];
  int tid = threadIdx.x;
  int lane = tid & 63, w = tid >> 6;
  int l15 = lane & 15, quad = lane >> 4;
  int mb = blockIdx.y * 64, nb = blockIdx.x * 64;
  int mq = (w & 1) * 32, nq = (w >> 1) * 32;
  const bf16* agp = Ob + (size_t)(mb + w * 16 + (lane >> 2)) * 1024 + (lane & 3) * 8;
  const bf16* bgp = wob + (size_t)(nb + w * 16 + (lane >> 2)) * 1024 + (lane & 3) * 8;
  bf16* alp = As + (w * 16) * 32;
  bf16* blp = Bs + (w * 16) * 32;
  f32x4 acc[2][2];
#pragma unroll
  for (int i = 0; i < 2; ++i)
#pragma unroll
    for (int j = 0; j < 2; ++j)
      for (int r = 0; r < 4; ++r) acc[i][j][r] = 0.f;
  for (int kt = 0; kt < 32; ++kt) {
    gl_lds16(agp, alp);
    gl_lds16(bgp, blp);
    agp += 32; bgp += 32;
    __syncthreads();
    bf16x8 af[2], bfr[2];
#pragma unroll
    for (int mt = 0; mt < 2; ++mt)
      af[mt] = *(const bf16x8*)(As + (mq + mt * 16 + l15) * 32 + quad * 8);
#pragma unroll
    for (int nt = 0; nt < 2; ++nt)
      bfr[nt] = *(const bf16x8*)(Bs + (nq + nt * 16 + l15) * 32 + quad * 8);
#pragma unroll
    for (int mt = 0; mt < 2; ++mt)
#pragma unroll
      for (int nt = 0; nt < 2; ++nt)
        acc[mt][nt] = __builtin_amdgcn_mfma_f32_16x16x32_bf16(af[mt], bfr[nt], acc[mt][nt], 0, 0, 0);
    __syncthreads();
  }
#pragma unroll
  for (int mt = 0; mt < 2; ++mt)
#pragma unroll
    for (int nt = 0; nt < 2; ++nt)
#pragma unroll
      for (int r = 0; r < 4; ++r)
        out[(size_t)(mb + mq + mt * 16 + quad * 4 + r) * 1024 + nb + nq + nt * 16 + l15] = acc[mt][nt][r];
}

extern "C" void kernel_launch(void* const* d_in, const int* in_sizes, int n_in,
                              void* d_out, int out_size, void* d_ws, size_t ws_size,
                              hipStream_t stream) {
  const float* x  = (const float*)d_in[0];
  const float* wq = (const float*)d_in[1];
  const float* wk = (const float*)d_in[2];
  const float* wv = (const float*)d_in[3];
  const float* wo = (const float*)d_in[4];
  const int* pos  = (const int*)d_in[5];
  float* out = (float*)d_out;
  // ws layout (bf16 elems): xb[4M] | wb[4x1M] | Q[4M] | K[4M] | Vt[4M] | O[4M]
  bf16* wsb = (bf16*)d_ws;
  bf16* xb  = wsb;
  bf16* wb  = wsb + 4194304;
  bf16* Qb  = wsb + 8388608;
  bf16* Kb  = wsb + 12582912;
  bf16* Vtb = wsb + 16777216;
  bf16* Obf = wsb + 20971520;
  float* tab = (float*)Obf;  // 512 KB table, dead before attn writes Obf
  hipLaunchKernelGGL(cvt_kernel, dim3(8192), dim3(256), 0, stream, x, wq, wk, wv, wo, wsb);
  hipLaunchKernelGGL(rope_tab_kernel, dim3(256), dim3(256), 0, stream, pos, tab);
  hipLaunchKernelGGL(gemm_qkv_kernel, dim3(24, 32), dim3(256), 0, stream, xb, wb, tab, Qb, Kb, Vtb);
  hipLaunchKernelGGL(attn_kernel, dim3(1024), dim3(256), 0, stream, Qb, Kb, Vtb, Obf);
  hipLaunchKernelGGL(gemm_out_kernel, dim3(16, 64), dim3(256), 0, stream, Obf, wb + 3 * 1048576, out);
}

// Round 5
// 203.332 us; speedup vs baseline: 1.5814x; 1.1189x over previous
//
#include <hip/hip_runtime.h>

// Shapes (fixed per reference): B=2, L=2048, D=1024, H=16, Dh=64
typedef __bf16 bf16;
typedef __attribute__((ext_vector_type(8))) __bf16 bf16x8;
typedef __attribute__((ext_vector_type(4))) __bf16 bf16x4;
typedef __attribute__((ext_vector_type(4))) float f32x4;

__device__ inline bf16 f2bf(float f) {
  unsigned u = __builtin_bit_cast(unsigned, f);
  u += 0x7fff + ((u >> 16) & 1);  // RNE
  unsigned short h = (unsigned short)(u >> 16);
  return __builtin_bit_cast(bf16, h);
}

__device__ inline void gl_lds16(const bf16* g, bf16* l) {
  __builtin_amdgcn_global_load_lds(
      (const __attribute__((address_space(1))) void*)g,
      (__attribute__((address_space(3))) void*)l, 16, 0, 0);
}

// ---------------- fp32 -> bf16 conversion + fused RoPE table --------------
// blocks < 8192: cvt x and the four W's. blocks >= 8192: build cos/sin table
// tab[tok*64 + 2j] = {cos,sin} (2048 x 32 x float2 = 512 KB, in dead Obf ws).
__global__ __launch_bounds__(256) void cvt_kernel(
    const float* __restrict__ x, const float* __restrict__ wq,
    const float* __restrict__ wk, const float* __restrict__ wv,
    const float* __restrict__ wo, bf16* __restrict__ dst,
    const int* __restrict__ pos, float* __restrict__ tab) {
  if (blockIdx.x >= 8192) {
    int gid = (blockIdx.x - 8192) * 256 + threadIdx.x;  // 65536 items
    int tok = gid >> 5, j = gid & 31;
    float freq = exp2f(-(float)(2 * j) * 0.20762051f);
    float angle = (float)pos[tok] * freq;
    float sn, cs;
    sincosf(angle, &sn, &cs);
    *(float2*)(tab + tok * 64 + j * 2) = make_float2(cs, sn);
    return;
  }
  int idx = (blockIdx.x * 256 + threadIdx.x) * 4;
  const float* src;
  if (idx < 4194304) {
    src = x + idx;
  } else {
    int j = idx - 4194304;
    int w = j >> 20;  // uniform per block
    const float* sw = (w == 0) ? wq : (w == 1) ? wk : (w == 2) ? wv : wo;
    src = sw + (j & 1048575);
  }
  float4 f = *(const float4*)src;
  bf16x4 o = {f2bf(f.x), f2bf(f.y), f2bf(f.z), f2bf(f.w)};
  *(bf16x4*)(dst + idx) = o;
}

// ---------------- QKV projection GEMM + RoPE epilogue ---------------------
// R14: (1) BK=64 (16 k-steps; halves barrier drains; 32 MFMA per drain) with
// XOR-granule LDS swizzle (pre-swizzled global src + linear gl_lds dest,
// read at granule^(row&7) -> ~2-way conflicts). (2) Block-uniform dest:
// N-tiles 0-7=Q, 8-15=K (RoPE path), 16-23=V (LDS-transpose path, coalesced
// 256B Vt segments instead of 2B/4KB-stride scatter). (3) XCD-chunked
// swizzle: each XCD gets 4 contiguous M-rows x 24 N-tiles (xb L2-resident).
__global__ __launch_bounds__(256) void gemm_qkv_kernel(
    const bf16* __restrict__ xb, const bf16* __restrict__ wb,
    const float* __restrict__ tab,
    bf16* __restrict__ Qb, bf16* __restrict__ Kb, bf16* __restrict__ Vtb) {
  __shared__ __align__(16) bf16 smem[16384];  // As[8192]|Bs[8192]; epi T[64*136]
  bf16* As = smem;
  bf16* Bs = smem + 8192;
  int tid = threadIdx.x;
  int lane = tid & 63, w = tid >> 6;
  int l15 = lane & 15, quad = lane >> 4;
  int bid = blockIdx.x;
  int sb = (bid & 7) * 96 + (bid >> 3);  // XCD-contiguous chunks (768 = 8*96)
  int bx = sb % 24, by = sb / 24;
  int mb = by * 128, nb = bx * 128;
  int mq = (w & 1) * 64, nq = (w >> 1) * 64;
  int gsw = (lane & 7) ^ ((lane >> 3) & 7);  // staging source granule swizzle
  const bf16* agp = xb + (size_t)(mb + w * 32 + (lane >> 3)) * 1024 + gsw * 8;
  const bf16* bgp = wb + (size_t)(nb + w * 32 + (lane >> 3)) * 1024 + gsw * 8;
  bf16* alp = As + (w * 32) * 64;  // + lane*16B linear (HW)
  bf16* blp = Bs + (w * 32) * 64;
  f32x4 acc[4][4];
#pragma unroll
  for (int i = 0; i < 4; ++i)
#pragma unroll
    for (int j = 0; j < 4; ++j)
      for (int r = 0; r < 4; ++r) acc[i][j][r] = 0.f;
  for (int kt = 0; kt < 16; ++kt) {
#pragma unroll
    for (int i = 0; i < 4; ++i) {
      gl_lds16(agp + i * 8192, alp + i * 512);  // i*8 rows
      gl_lds16(bgp + i * 8192, blp + i * 512);
    }
    agp += 64; bgp += 64;
    __syncthreads();
#pragma unroll
    for (int c = 0; c < 2; ++c) {
      bf16x8 af[4], bfr[4];
      int rg = (c * 4 + quad);
#pragma unroll
      for (int mt = 0; mt < 4; ++mt)
        af[mt] = *(const bf16x8*)(As + (mq + mt * 16 + l15) * 64 + (rg ^ (l15 & 7)) * 8);
#pragma unroll
      for (int nt = 0; nt < 4; ++nt)
        bfr[nt] = *(const bf16x8*)(Bs + (nq + nt * 16 + l15) * 64 + (rg ^ (l15 & 7)) * 8);
#pragma unroll
      for (int mt = 0; mt < 4; ++mt)
#pragma unroll
        for (int nt = 0; nt < 4; ++nt)
          acc[mt][nt] = __builtin_amdgcn_mfma_f32_16x16x32_bf16(af[mt], bfr[nt], acc[mt][nt], 0, 0, 0);
    }
    __syncthreads();
  }
  int b = mb >> 11;        // block-uniform batch
  int mtok = mb & 2047;    // block-uniform token base
  if (bx < 16) {
    // ---- Q or K tile: RoPE epilogue (C col=l15 -> e, row=quad*4+r -> tok)
    bf16* dst = (bx < 8) ? Qb : Kb;
#pragma unroll
    for (int nt = 0; nt < 4; ++nt) {
      int e = nb + nq + nt * 16 + l15;
      int d = e & 63;
      int h = (e & 1023) >> 6;
      int tbase = d & ~1;
#pragma unroll
      for (int mt = 0; mt < 4; ++mt) {
#pragma unroll
        for (int r = 0; r < 4; ++r) {
          int ltok = mtok + mq + mt * 16 + quad * 4 + r;
          float val = acc[mt][nt][r];
          float p = __shfl_xor(val, 1);
          float2 cs2 = *(const float2*)(tab + ltok * 64 + tbase);
          float outv = (e & 1) ? (p * cs2.y + val * cs2.x) : (val * cs2.x - p * cs2.y);
          dst[(size_t)(((b << 4) + h) * 2048 + ltok) * 64 + d] = f2bf(outv);
        }
      }
    }
  } else {
    // ---- V tile: transpose via LDS (smem dead after K-loop), coalesced Vt
    bf16* T = smem;  // [64][136] bf16 = 17408 B <= 32 KB
    for (int h2 = 0; h2 < 2; ++h2) {
      if ((w >> 1) == h2) {  // waves owning cols [h2*64, h2*64+64)
#pragma unroll
        for (int nt = 0; nt < 4; ++nt)
#pragma unroll
          for (int mt = 0; mt < 4; ++mt) {
            bf16x4 tv = {f2bf(acc[mt][nt][0]), f2bf(acc[mt][nt][1]),
                         f2bf(acc[mt][nt][2]), f2bf(acc[mt][nt][3])};
            *(bf16x4*)&T[(nt * 16 + l15) * 136 + mq + mt * 16 + quad * 4] = tv;
          }
      }
      __syncthreads();
      int row = tid >> 2, cs = (tid & 3) * 32;
      int e = nb + h2 * 64 + row;
      int d = e & 63, hh = (e & 1023) >> 6;
      bf16* vdst = Vtb + ((size_t)((b << 4) + hh) * 64 + d) * 2048 + mtok + cs;
#pragma unroll
      for (int j = 0; j < 4; ++j)
        *(bf16x8*)(vdst + j * 8) = *(const bf16x8*)&T[row * 136 + cs + j * 8];
      __syncthreads();
    }
  }
}

// ---------------- causal flash attention v8 (R10 verbatim, frozen) ---------
#define SCALE_L2E 0.18033688f  // 0.125 * log2(e)
__global__ __launch_bounds__(256) void attn_kernel(
    const bf16* __restrict__ Qb, const bf16* __restrict__ Kb,
    const bf16* __restrict__ Vtb, bf16* __restrict__ Ob) {
  __shared__ __align__(16) bf16 Ks[64 * 64];
  __shared__ __align__(16) bf16 Vs[64 * 64];
  __shared__ __align__(16) bf16 pbuf[4][16 * 72];
  int tid = threadIdx.x;
  int lane = tid & 63, w = tid >> 6;
  int l15 = lane & 15, quad = lane >> 4;
  int bidx = blockIdx.x;
  int bh = bidx & 31;
  int qt = 31 - (bidx >> 5);  // LPT: longest q-tiles dispatch first
  int qbase = qt * 64;
  const bf16* Qp = Qb + (size_t)bh * 131072;
  const bf16* Kp = Kb + (size_t)bh * 131072;
  const bf16* Vp = Vtb + (size_t)bh * 131072;
  int r8 = lane >> 3;
  int gsw8 = (lane & 7) ^ r8;       // staging source granule swizzle
  int g0 = quad ^ (l15 & 7);        // read granule, k-chunk 0
  int g1 = (4 + quad) ^ (l15 & 7);  // read granule, k-chunk 1
  bf16x8 qf[2];
#pragma unroll
  for (int c = 0; c < 2; ++c)
    qf[c] = *(const bf16x8*)(Qp + (size_t)(qbase + w * 16 + l15) * 64 + c * 32 + quad * 8);
  f32x4 oacc[4];
#pragma unroll
  for (int dt = 0; dt < 4; ++dt)
    for (int r = 0; r < 4; ++r) oacc[dt][r] = 0.f;
  float lpart = 0.f;  // per-lane partial denominator
  int qmin_w = qbase + w * 16;
  int qmax_w = qmin_w + 15;
  int ntiles = qt + 1;

  for (int t = 0; t < ntiles; ++t) {
    int kb = t * 64;
    {  // stage tile t (single buffer): wave w covers rows [w*16, w*16+16)
      const bf16* ksrc = Kp + (size_t)(kb + w * 16 + r8) * 64 + gsw8 * 8;
      bf16* kdst = &Ks[(w * 16) * 64];
      gl_lds16(ksrc, kdst);
      gl_lds16(ksrc + 8 * 64, kdst + 8 * 64);
      const bf16* vsrc = Vp + (size_t)(w * 16 + r8) * 2048 + kb + gsw8 * 8;
      bf16* vdst = &Vs[(w * 16) * 64];
      gl_lds16(vsrc, vdst);
      gl_lds16(vsrc + 8 * 2048, vdst + 8 * 64);
    }
    __syncthreads();  // DMA drained
    if (kb <= qmax_w) {  // wave-uniform: skip compute on fully-masked tiles
      bf16x8 kf[4][2], vf[4][2];
#pragma unroll
      for (int kt = 0; kt < 4; ++kt) {
        kf[kt][0] = *(const bf16x8*)(&Ks[(kt * 16 + l15) * 64 + g0 * 8]);
        kf[kt][1] = *(const bf16x8*)(&Ks[(kt * 16 + l15) * 64 + g1 * 8]);
      }
#pragma unroll
      for (int dt = 0; dt < 4; ++dt) {
        vf[dt][0] = *(const bf16x8*)(&Vs[(dt * 16 + l15) * 64 + g0 * 8]);
        vf[dt][1] = *(const bf16x8*)(&Vs[(dt * 16 + l15) * 64 + g1 * 8]);
      }
      int q = qmin_w + l15;
      f32x4 s[4];
#pragma unroll
      for (int kt = 0; kt < 4; ++kt) {
        for (int r = 0; r < 4; ++r) s[kt][r] = 0.f;
        s[kt] = __builtin_amdgcn_mfma_f32_16x16x32_bf16(kf[kt][0], qf[0], s[kt], 0, 0, 0);
        s[kt] = __builtin_amdgcn_mfma_f32_16x16x32_bf16(kf[kt][1], qf[1], s[kt], 0, 0, 0);
      }
      float pe[16];
      if (kb + 63 > qmin_w) {  // diagonal: per-element mask (wave-uniform test)
#pragma unroll
        for (int kt = 0; kt < 4; ++kt)
#pragma unroll
          for (int r = 0; r < 4; ++r) {
            int key = kb + kt * 16 + quad * 4 + r;
            pe[kt * 4 + r] = (key <= q) ? exp2f(s[kt][r] * SCALE_L2E) : 0.f;
          }
      } else {
#pragma unroll
        for (int kt = 0; kt < 4; ++kt)
#pragma unroll
          for (int r = 0; r < 4; ++r) pe[kt * 4 + r] = exp2f(s[kt][r] * SCALE_L2E);
      }
#pragma unroll
      for (int i = 0; i < 16; ++i) lpart += pe[i];
#pragma unroll
      for (int kt = 0; kt < 4; ++kt) {
        bf16x4 pw = {f2bf(pe[kt * 4]), f2bf(pe[kt * 4 + 1]), f2bf(pe[kt * 4 + 2]), f2bf(pe[kt * 4 + 3])};
        *(bf16x4*)&pbuf[w][l15 * 72 + kt * 16 + quad * 4] = pw;
      }
      // same-wave LDS round-trip: lgkmcnt ordering only, no barrier
      bf16x8 pb0 = *(const bf16x8*)&pbuf[w][l15 * 72 + quad * 8];
      bf16x8 pb1 = *(const bf16x8*)&pbuf[w][l15 * 72 + 32 + quad * 8];
#pragma unroll
      for (int dt = 0; dt < 4; ++dt) {
        oacc[dt] = __builtin_amdgcn_mfma_f32_16x16x32_bf16(vf[dt][0], pb0, oacc[dt], 0, 0, 0);
        oacc[dt] = __builtin_amdgcn_mfma_f32_16x16x32_bf16(vf[dt][1], pb1, oacc[dt], 0, 0, 0);
      }
    }
    __syncthreads();  // all reads of Ks/Vs done before next stage
  }
  float lrun = lpart;
  lrun += __shfl_xor(lrun, 16);
  lrun += __shfl_xor(lrun, 32);
  int b0 = bh >> 4, h = bh & 15;
  float inv = 1.f / lrun;
  int q = qmin_w + l15;
  bf16* obase = Ob + ((size_t)(b0 * 2048 + q)) * 1024 + h * 64;
#pragma unroll
  for (int dt = 0; dt < 4; ++dt)
#pragma unroll
    for (int r = 0; r < 4; ++r)
      obase[dt * 16 + quad * 4 + r] = f2bf(oacc[dt][r] * inv);
}

// ---------------- output projection GEMM (64x64 tile, fp32 out, frozen) ----
__global__ __launch_bounds__(256) void gemm_out_kernel(
    const bf16* __restrict__ Ob, const bf16* __restrict__ wob,
    float* __restrict__ out) {
  __shared__ __align__(16) bf16 As[64 * 32];
  __shared__ __align__(16) bf16 Bs[64 * 32];
  int tid = threadIdx.x;
  int lane = tid & 63, w = tid >> 6;
  int l15 = lane & 15, quad = lane >> 4;
  int mb = blockIdx.y * 64, nb = blockIdx.x * 64;
  int mq = (w & 1) * 32, nq = (w >> 1) * 32;
  const bf16* agp = Ob + (size_t)(mb + w * 16 + (lane >> 2)) * 1024 + (lane & 3) * 8;
  const bf16* bgp = wob + (size_t)(nb + w * 16 + (lane >> 2)) * 1024 + (lane & 3) * 8;
  bf16* alp = As + (w * 16) * 32;
  bf16* blp = Bs + (w * 16) * 32;
  f32x4 acc[2][2];
#pragma unroll
  for (int i = 0; i < 2; ++i)
#pragma unroll
    for (int j = 0; j < 2; ++j)
      for (int r = 0; r < 4; ++r) acc[i][j][r] = 0.f;
  for (int kt = 0; kt < 32; ++kt) {
    gl_lds16(agp, alp);
    gl_lds16(bgp, blp);
    agp += 32; bgp += 32;
    __syncthreads();
    bf16x8 af[2], bfr[2];
#pragma unroll
    for (int mt = 0; mt < 2; ++mt)
      af[mt] = *(const bf16x8*)(As + (mq + mt * 16 + l15) * 32 + quad * 8);
#pragma unroll
    for (int nt = 0; nt < 2; ++nt)
      bfr[nt] = *(const bf16x8*)(Bs + (nq + nt * 16 + l15) * 32 + quad * 8);
#pragma unroll
    for (int mt = 0; mt < 2; ++mt)
#pragma unroll
      for (int nt = 0; nt < 2; ++nt)
        acc[mt][nt] = __builtin_amdgcn_mfma_f32_16x16x32_bf16(af[mt], bfr[nt], acc[mt][nt], 0, 0, 0);
    __syncthreads();
  }
#pragma unroll
  for (int mt = 0; mt < 2; ++mt)
#pragma unroll
    for (int nt = 0; nt < 2; ++nt)
#pragma unroll
      for (int r = 0; r < 4; ++r)
        out[(size_t)(mb + mq + mt * 16 + quad * 4 + r) * 1024 + nb + nq + nt * 16 + l15] = acc[mt][nt][r];
}

extern "C" void kernel_launch(void* const* d_in, const int* in_sizes, int n_in,
                              void* d_out, int out_size, void* d_ws, size_t ws_size,
                              hipStream_t stream) {
  const float* x  = (const float*)d_in[0];
  const float* wq = (const float*)d_in[1];
  const float* wk = (const float*)d_in[2];
  const float* wv = (const float*)d_in[3];
  const float* wo = (const float*)d_in[4];
  const int* pos  = (const int*)d_in[5];
  float* out = (float*)d_out;
  // ws layout (bf16 elems): xb[4M] | wb[4x1M] | Q[4M] | K[4M] | Vt[4M] | O[4M]
  bf16* wsb = (bf16*)d_ws;
  bf16* xb  = wsb;
  bf16* wb  = wsb + 4194304;
  bf16* Qb  = wsb + 8388608;
  bf16* Kb  = wsb + 12582912;
  bf16* Vtb = wsb + 16777216;
  bf16* Obf = wsb + 20971520;
  float* tab = (float*)Obf;  // 512 KB table, dead before attn writes Obf
  hipLaunchKernelGGL(cvt_kernel, dim3(8448), dim3(256), 0, stream, x, wq, wk, wv, wo, wsb, pos, tab);
  hipLaunchKernelGGL(gemm_qkv_kernel, dim3(768), dim3(256), 0, stream, xb, wb, tab, Qb, Kb, Vtb);
  hipLaunchKernelGGL(attn_kernel, dim3(1024), dim3(256), 0, stream, Qb, Kb, Vtb, Obf);
  hipLaunchKernelGGL(gemm_out_kernel, dim3(16, 64), dim3(256), 0, stream, Obf, wb + 3 * 1048576, out);
}

// Round 8
// 201.652 us; speedup vs baseline: 1.5945x; 1.0083x over previous
//
#include <hip/hip_runtime.h>

// Shapes (fixed per reference): B=2, L=2048, D=1024, H=16, Dh=64
typedef __bf16 bf16;
typedef __attribute__((ext_vector_type(8))) __bf16 bf16x8;
typedef __attribute__((ext_vector_type(4))) __bf16 bf16x4;
typedef __attribute__((ext_vector_type(4))) float f32x4;

__device__ inline bf16 f2bf(float f) {
  unsigned u = __builtin_bit_cast(unsigned, f);
  u += 0x7fff + ((u >> 16) & 1);  // RNE
  unsigned short h = (unsigned short)(u >> 16);
  return __builtin_bit_cast(bf16, h);
}

__device__ inline void gl_lds16(const bf16* g, bf16* l) {
  __builtin_amdgcn_global_load_lds(
      (const __attribute__((address_space(1))) void*)g,
      (__attribute__((address_space(3))) void*)l, 16, 0, 0);
}

// ---------------- fp32 -> bf16 conversion + fused RoPE table --------------
__global__ __launch_bounds__(256) void cvt_kernel(
    const float* __restrict__ x, const float* __restrict__ wq,
    const float* __restrict__ wk, const float* __restrict__ wv,
    const float* __restrict__ wo, bf16* __restrict__ dst,
    const int* __restrict__ pos, float* __restrict__ tab) {
  if (blockIdx.x >= 8192) {
    int gid = (blockIdx.x - 8192) * 256 + threadIdx.x;  // 65536 items
    int tok = gid >> 5, j = gid & 31;
    float freq = exp2f(-(float)(2 * j) * 0.20762051f);
    float angle = (float)pos[tok] * freq;
    float sn, cs;
    sincosf(angle, &sn, &cs);
    *(float2*)(tab + tok * 64 + j * 2) = make_float2(cs, sn);
    return;
  }
  int idx = (blockIdx.x * 256 + threadIdx.x) * 4;
  const float* src;
  if (idx < 4194304) {
    src = x + idx;
  } else {
    int j = idx - 4194304;
    int w = j >> 20;  // uniform per block
    const float* sw = (w == 0) ? wq : (w == 1) ? wk : (w == 2) ? wv : wo;
    src = sw + (j & 1048575);
  }
  float4 f = *(const float4*)src;
  bf16x4 o = {f2bf(f.x), f2bf(f.y), f2bf(f.z), f2bf(f.w)};
  *(bf16x4*)(dst + idx) = o;
}

// ---------------- QKV projection GEMM + RoPE epilogue ---------------------
// R15: balanced XCD region. R14's (4 rows x 24 cols)/XCD put all 6 MB of wb
// in every XCD's 4 MB L2 -> thrash (FETCH 43->80.7 MB). Now each XCD's 96
// concurrent blocks span 8 rows x 12 cols: 2 MB (A) + 3 MB (B) = 5 MB
// working set, near-L2-fit. K-loop/epilogue unchanged from R14 (bank
// conflicts 65K, WRITE ideal 24.6 MB).
__global__ __launch_bounds__(256) void gemm_qkv_kernel(
    const bf16* __restrict__ xb, const bf16* __restrict__ wb,
    const float* __restrict__ tab,
    bf16* __restrict__ Qb, bf16* __restrict__ Kb, bf16* __restrict__ Vtb) {
  __shared__ __align__(16) bf16 smem[16384];  // As[8192]|Bs[8192]; epi T[64*136]
  bf16* As = smem;
  bf16* Bs = smem + 8192;
  int tid = threadIdx.x;
  int lane = tid & 63, w = tid >> 6;
  int l15 = lane & 15, quad = lane >> 4;
  int bid = blockIdx.x;
  int xcd = bid & 7, j = bid >> 3;       // XCD round-robin; j in [0,96)
  int by = (xcd & 3) * 8 + (j & 7);      // 32 M-tiles, 8 per XCD row-group
  int bx = (xcd >> 2) * 12 + (j >> 3);   // 24 N-tiles, 12 per XCD col-group
  int mb = by * 128, nb = bx * 128;
  int mq = (w & 1) * 64, nq = (w >> 1) * 64;
  int gsw = (lane & 7) ^ ((lane >> 3) & 7);  // staging source granule swizzle
  const bf16* agp = xb + (size_t)(mb + w * 32 + (lane >> 3)) * 1024 + gsw * 8;
  const bf16* bgp = wb + (size_t)(nb + w * 32 + (lane >> 3)) * 1024 + gsw * 8;
  bf16* alp = As + (w * 32) * 64;  // + lane*16B linear (HW)
  bf16* blp = Bs + (w * 32) * 64;
  f32x4 acc[4][4];
#pragma unroll
  for (int i = 0; i < 4; ++i)
#pragma unroll
    for (int j2 = 0; j2 < 4; ++j2)
      for (int r = 0; r < 4; ++r) acc[i][j2][r] = 0.f;
  for (int kt = 0; kt < 16; ++kt) {
#pragma unroll
    for (int i = 0; i < 4; ++i) {
      gl_lds16(agp + i * 8192, alp + i * 512);  // i*8 rows
      gl_lds16(bgp + i * 8192, blp + i * 512);
    }
    agp += 64; bgp += 64;
    __syncthreads();
#pragma unroll
    for (int c = 0; c < 2; ++c) {
      bf16x8 af[4], bfr[4];
      int rg = (c * 4 + quad);
#pragma unroll
      for (int mt = 0; mt < 4; ++mt)
        af[mt] = *(const bf16x8*)(As + (mq + mt * 16 + l15) * 64 + (rg ^ (l15 & 7)) * 8);
#pragma unroll
      for (int nt = 0; nt < 4; ++nt)
        bfr[nt] = *(const bf16x8*)(Bs + (nq + nt * 16 + l15) * 64 + (rg ^ (l15 & 7)) * 8);
#pragma unroll
      for (int mt = 0; mt < 4; ++mt)
#pragma unroll
        for (int nt = 0; nt < 4; ++nt)
          acc[mt][nt] = __builtin_amdgcn_mfma_f32_16x16x32_bf16(af[mt], bfr[nt], acc[mt][nt], 0, 0, 0);
    }
    __syncthreads();
  }
  int b = mb >> 11;        // block-uniform batch
  int mtok = mb & 2047;    // block-uniform token base
  if (bx < 16) {
    // ---- Q or K tile: RoPE epilogue (C col=l15 -> e, row=quad*4+r -> tok)
    bf16* dst = (bx < 8) ? Qb : Kb;
#pragma unroll
    for (int nt = 0; nt < 4; ++nt) {
      int e = nb + nq + nt * 16 + l15;
      int d = e & 63;
      int h = (e & 1023) >> 6;
      int tbase = d & ~1;
#pragma unroll
      for (int mt = 0; mt < 4; ++mt) {
#pragma unroll
        for (int r = 0; r < 4; ++r) {
          int ltok = mtok + mq + mt * 16 + quad * 4 + r;
          float val = acc[mt][nt][r];
          float p = __shfl_xor(val, 1);
          float2 cs2 = *(const float2*)(tab + ltok * 64 + tbase);
          float outv = (e & 1) ? (p * cs2.y + val * cs2.x) : (val * cs2.x - p * cs2.y);
          dst[(size_t)(((b << 4) + h) * 2048 + ltok) * 64 + d] = f2bf(outv);
        }
      }
    }
  } else {
    // ---- V tile: transpose via LDS (smem dead after K-loop), coalesced Vt
    bf16* T = smem;  // [64][136] bf16 = 17408 B
    for (int h2 = 0; h2 < 2; ++h2) {
      if ((w >> 1) == h2) {  // waves owning cols [h2*64, h2*64+64)
#pragma unroll
        for (int nt = 0; nt < 4; ++nt)
#pragma unroll
          for (int mt = 0; mt < 4; ++mt) {
            bf16x4 tv = {f2bf(acc[mt][nt][0]), f2bf(acc[mt][nt][1]),
                         f2bf(acc[mt][nt][2]), f2bf(acc[mt][nt][3])};
            *(bf16x4*)&T[(nt * 16 + l15) * 136 + mq + mt * 16 + quad * 4] = tv;
          }
      }
      __syncthreads();
      int row = tid >> 2, cs = (tid & 3) * 32;
      int e = nb + h2 * 64 + row;
      int d = e & 63, hh = (e & 1023) >> 6;
      bf16* vdst = Vtb + ((size_t)((b << 4) + hh) * 64 + d) * 2048 + mtok + cs;
#pragma unroll
      for (int j3 = 0; j3 < 4; ++j3)
        *(bf16x8*)(vdst + j3 * 8) = *(const bf16x8*)&T[row * 136 + cs + j3 * 8];
      __syncthreads();
    }
  }
}

// ---------------- causal flash attention v8 (R10 verbatim, frozen) ---------
#define SCALE_L2E 0.18033688f  // 0.125 * log2(e)
__global__ __launch_bounds__(256) void attn_kernel(
    const bf16* __restrict__ Qb, const bf16* __restrict__ Kb,
    const bf16* __restrict__ Vtb, bf16* __restrict__ Ob) {
  __shared__ __align__(16) bf16 Ks[64 * 64];
  __shared__ __align__(16) bf16 Vs[64 * 64];
  __shared__ __align__(16) bf16 pbuf[4][16 * 72];
  int tid = threadIdx.x;
  int lane = tid & 63, w = tid >> 6;
  int l15 = lane & 15, quad = lane >> 4;
  int bidx = blockIdx.x;
  int bh = bidx & 31;
  int qt = 31 - (bidx >> 5);  // LPT: longest q-tiles dispatch first
  int qbase = qt * 64;
  const bf16* Qp = Qb + (size_t)bh * 131072;
  const bf16* Kp = Kb + (size_t)bh * 131072;
  const bf16* Vp = Vtb + (size_t)bh * 131072;
  int r8 = lane >> 3;
  int gsw8 = (lane & 7) ^ r8;       // staging source granule swizzle
  int g0 = quad ^ (l15 & 7);        // read granule, k-chunk 0
  int g1 = (4 + quad) ^ (l15 & 7);  // read granule, k-chunk 1
  bf16x8 qf[2];
#pragma unroll
  for (int c = 0; c < 2; ++c)
    qf[c] = *(const bf16x8*)(Qp + (size_t)(qbase + w * 16 + l15) * 64 + c * 32 + quad * 8);
  f32x4 oacc[4];
#pragma unroll
  for (int dt = 0; dt < 4; ++dt)
    for (int r = 0; r < 4; ++r) oacc[dt][r] = 0.f;
  float lpart = 0.f;  // per-lane partial denominator
  int qmin_w = qbase + w * 16;
  int qmax_w = qmin_w + 15;
  int ntiles = qt + 1;

  for (int t = 0; t < ntiles; ++t) {
    int kb = t * 64;
    {  // stage tile t (single buffer): wave w covers rows [w*16, w*16+16)
      const bf16* ksrc = Kp + (size_t)(kb + w * 16 + r8) * 64 + gsw8 * 8;
      bf16* kdst = &Ks[(w * 16) * 64];
      gl_lds16(ksrc, kdst);
      gl_lds16(ksrc + 8 * 64, kdst + 8 * 64);
      const bf16* vsrc = Vp + (size_t)(w * 16 + r8) * 2048 + kb + gsw8 * 8;
      bf16* vdst = &Vs[(w * 16) * 64];
      gl_lds16(vsrc, vdst);
      gl_lds16(vsrc + 8 * 2048, vdst + 8 * 64);
    }
    __syncthreads();  // DMA drained
    if (kb <= qmax_w) {  // wave-uniform: skip compute on fully-masked tiles
      bf16x8 kf[4][2], vf[4][2];
#pragma unroll
      for (int kt = 0; kt < 4; ++kt) {
        kf[kt][0] = *(const bf16x8*)(&Ks[(kt * 16 + l15) * 64 + g0 * 8]);
        kf[kt][1] = *(const bf16x8*)(&Ks[(kt * 16 + l15) * 64 + g1 * 8]);
      }
#pragma unroll
      for (int dt = 0; dt < 4; ++dt) {
        vf[dt][0] = *(const bf16x8*)(&Vs[(dt * 16 + l15) * 64 + g0 * 8]);
        vf[dt][1] = *(const bf16x8*)(&Vs[(dt * 16 + l15) * 64 + g1 * 8]);
      }
      int q = qmin_w + l15;
      f32x4 s[4];
#pragma unroll
      for (int kt = 0; kt < 4; ++kt) {
        for (int r = 0; r < 4; ++r) s[kt][r] = 0.f;
        s[kt] = __builtin_amdgcn_mfma_f32_16x16x32_bf16(kf[kt][0], qf[0], s[kt], 0, 0, 0);
        s[kt] = __builtin_amdgcn_mfma_f32_16x16x32_bf16(kf[kt][1], qf[1], s[kt], 0, 0, 0);
      }
      float pe[16];
      if (kb + 63 > qmin_w) {  // diagonal: per-element mask (wave-uniform test)
#pragma unroll
        for (int kt = 0; kt < 4; ++kt)
#pragma unroll
          for (int r = 0; r < 4; ++r) {
            int key = kb + kt * 16 + quad * 4 + r;
            pe[kt * 4 + r] = (key <= q) ? exp2f(s[kt][r] * SCALE_L2E) : 0.f;
          }
      } else {
#pragma unroll
        for (int kt = 0; kt < 4; ++kt)
#pragma unroll
          for (int r = 0; r < 4; ++r) pe[kt * 4 + r] = exp2f(s[kt][r] * SCALE_L2E);
      }
#pragma unroll
      for (int i = 0; i < 16; ++i) lpart += pe[i];
#pragma unroll
      for (int kt = 0; kt < 4; ++kt) {
        bf16x4 pw = {f2bf(pe[kt * 4]), f2bf(pe[kt * 4 + 1]), f2bf(pe[kt * 4 + 2]), f2bf(pe[kt * 4 + 3])};
        *(bf16x4*)&pbuf[w][l15 * 72 + kt * 16 + quad * 4] = pw;
      }
      // same-wave LDS round-trip: lgkmcnt ordering only, no barrier
      bf16x8 pb0 = *(const bf16x8*)&pbuf[w][l15 * 72 + quad * 8];
      bf16x8 pb1 = *(const bf16x8*)&pbuf[w][l15 * 72 + 32 + quad * 8];
#pragma unroll
      for (int dt = 0; dt < 4; ++dt) {
        oacc[dt] = __builtin_amdgcn_mfma_f32_16x16x32_bf16(vf[dt][0], pb0, oacc[dt], 0, 0, 0);
        oacc[dt] = __builtin_amdgcn_mfma_f32_16x16x32_bf16(vf[dt][1], pb1, oacc[dt], 0, 0, 0);
      }
    }
    __syncthreads();  // all reads of Ks/Vs done before next stage
  }
  float lrun = lpart;
  lrun += __shfl_xor(lrun, 16);
  lrun += __shfl_xor(lrun, 32);
  int b0 = bh >> 4, h = bh & 15;
  float inv = 1.f / lrun;
  int q = qmin_w + l15;
  bf16* obase = Ob + ((size_t)(b0 * 2048 + q)) * 1024 + h * 64;
#pragma unroll
  for (int dt = 0; dt < 4; ++dt)
#pragma unroll
    for (int r = 0; r < 4; ++r)
      obase[dt * 16 + quad * 4 + r] = f2bf(oacc[dt][r] * inv);
}

// ---------------- output projection GEMM ------------------------------------
// R15: ported to the R14 K-loop structure. Old 64^2/BK=32 version was the
// hidden #2 cost (~45 us at ~190 TF). Now BM=128 x BN=64, BK=64, 16 MFMA :
// 6 gl_lds16 per k-step per wave, XOR-granule swizzle, grid 512 = 2
// blocks/CU (8 waves/CU for latency hiding), balanced XCD regions (8 rows x
// 8 cols: A 2 MB + B 1 MB = 3 MB < 4 MB L2).
__global__ __launch_bounds__(256) void gemm_out_kernel(
    const bf16* __restrict__ Ob, const bf16* __restrict__ wob,
    float* __restrict__ out) {
  __shared__ __align__(16) bf16 As[128 * 64];
  __shared__ __align__(16) bf16 Bs[64 * 64];
  int tid = threadIdx.x;
  int lane = tid & 63, w = tid >> 6;
  int l15 = lane & 15, quad = lane >> 4;
  int bid = blockIdx.x;
  int xcd = bid & 7, j = bid >> 3;       // j in [0,64)
  int by = (xcd & 3) * 8 + (j & 7);      // 32 M-tiles
  int bx = (xcd >> 2) * 8 + (j >> 3);    // 16 N-tiles
  int mb = by * 128, nb = bx * 64;
  int mq = (w & 1) * 64, nq = (w >> 1) * 32;
  int gsw = (lane & 7) ^ ((lane >> 3) & 7);
  const bf16* agp = Ob + (size_t)(mb + w * 32 + (lane >> 3)) * 1024 + gsw * 8;
  const bf16* bgp = wob + (size_t)(nb + w * 16 + (lane >> 3)) * 1024 + gsw * 8;
  bf16* alp = As + (w * 32) * 64;
  bf16* blp = Bs + (w * 16) * 64;
  f32x4 acc[4][2];
#pragma unroll
  for (int i = 0; i < 4; ++i)
#pragma unroll
    for (int j2 = 0; j2 < 2; ++j2)
      for (int r = 0; r < 4; ++r) acc[i][j2][r] = 0.f;
  for (int kt = 0; kt < 16; ++kt) {
#pragma unroll
    for (int i = 0; i < 4; ++i)
      gl_lds16(agp + i * 8192, alp + i * 512);  // i*8 rows of A
#pragma unroll
    for (int i = 0; i < 2; ++i)
      gl_lds16(bgp + i * 8192, blp + i * 512);  // i*8 rows of B
    agp += 64; bgp += 64;
    __syncthreads();
#pragma unroll
    for (int c = 0; c < 2; ++c) {
      bf16x8 af[4], bfr[2];
      int rg = (c * 4 + quad);
#pragma unroll
      for (int mt = 0; mt < 4; ++mt)
        af[mt] = *(const bf16x8*)(As + (mq + mt * 16 + l15) * 64 + (rg ^ (l15 & 7)) * 8);
#pragma unroll
      for (int nt = 0; nt < 2; ++nt)
        bfr[nt] = *(const bf16x8*)(Bs + (nq + nt * 16 + l15) * 64 + (rg ^ (l15 & 7)) * 8);
#pragma unroll
      for (int mt = 0; mt < 4; ++mt)
#pragma unroll
        for (int nt = 0; nt < 2; ++nt)
          acc[mt][nt] = __builtin_amdgcn_mfma_f32_16x16x32_bf16(af[mt], bfr[nt], acc[mt][nt], 0, 0, 0);
    }
    __syncthreads();
  }
#pragma unroll
  for (int mt = 0; mt < 4; ++mt)
#pragma unroll
    for (int nt = 0; nt < 2; ++nt)
#pragma unroll
      for (int r = 0; r < 4; ++r)
        out[(size_t)(mb + mq + mt * 16 + quad * 4 + r) * 1024 + nb + nq + nt * 16 + l15] = acc[mt][nt][r];
}

extern "C" void kernel_launch(void* const* d_in, const int* in_sizes, int n_in,
                              void* d_out, int out_size, void* d_ws, size_t ws_size,
                              hipStream_t stream) {
  const float* x  = (const float*)d_in[0];
  const float* wq = (const float*)d_in[1];
  const float* wk = (const float*)d_in[2];
  const float* wv = (const float*)d_in[3];
  const float* wo = (const float*)d_in[4];
  const int* pos  = (const int*)d_in[5];
  float* out = (float*)d_out;
  // ws layout (bf16 elems): xb[4M] | wb[4x1M] | Q[4M] | K[4M] | Vt[4M] | O[4M]
  bf16* wsb = (bf16*)d_ws;
  bf16* xb  = wsb;
  bf16* wb  = wsb + 4194304;
  bf16* Qb  = wsb + 8388608;
  bf16* Kb  = wsb + 12582912;
  bf16* Vtb = wsb + 16777216;
  bf16* Obf = wsb + 20971520;
  float* tab = (float*)Obf;  // 512 KB table, dead before attn writes Obf
  hipLaunchKernelGGL(cvt_kernel, dim3(8448), dim3(256), 0, stream, x, wq, wk, wv, wo, wsb, pos, tab);
  hipLaunchKernelGGL(gemm_qkv_kernel, dim3(768), dim3(256), 0, stream, xb, wb, tab, Qb, Kb, Vtb);
  hipLaunchKernelGGL(attn_kernel, dim3(1024), dim3(256), 0, stream, Qb, Kb, Vtb, Obf);
  hipLaunchKernelGGL(gemm_out_kernel, dim3(512), dim3(256), 0, stream, Obf, wb + 3 * 1048576, out);
}

// Round 13
// 190.246 us; speedup vs baseline: 1.6901x; 1.0600x over previous
//
#include <hip/hip_runtime.h>

// Shapes (fixed per reference): B=2, L=2048, D=1024, H=16, Dh=64
typedef __bf16 bf16;
typedef __attribute__((ext_vector_type(8))) __bf16 bf16x8;
typedef __attribute__((ext_vector_type(4))) __bf16 bf16x4;
typedef __attribute__((ext_vector_type(4))) float f32x4;

__device__ inline bf16 f2bf(float f) {
  unsigned u = __builtin_bit_cast(unsigned, f);
  u += 0x7fff + ((u >> 16) & 1);  // RNE
  unsigned short h = (unsigned short)(u >> 16);
  return __builtin_bit_cast(bf16, h);
}

__device__ inline void gl_lds16(const bf16* g, bf16* l) {
  __builtin_amdgcn_global_load_lds(
      (const __attribute__((address_space(1))) void*)g,
      (__attribute__((address_space(3))) void*)l, 16, 0, 0);
}

// ---------------- fp32 -> bf16 conversion + fused RoPE table --------------
__global__ __launch_bounds__(256) void cvt_kernel(
    const float* __restrict__ x, const float* __restrict__ wq,
    const float* __restrict__ wk, const float* __restrict__ wv,
    const float* __restrict__ wo, bf16* __restrict__ dst,
    const int* __restrict__ pos, float* __restrict__ tab) {
  if (blockIdx.x >= 8192) {
    int gid = (blockIdx.x - 8192) * 256 + threadIdx.x;  // 65536 items
    int tok = gid >> 5, j = gid & 31;
    float freq = exp2f(-(float)(2 * j) * 0.20762051f);
    float angle = (float)pos[tok] * freq;
    float sn, cs;
    sincosf(angle, &sn, &cs);
    *(float2*)(tab + tok * 64 + j * 2) = make_float2(cs, sn);
    return;
  }
  int idx = (blockIdx.x * 256 + threadIdx.x) * 4;
  const float* src;
  if (idx < 4194304) {
    src = x + idx;
  } else {
    int j = idx - 4194304;
    int w = j >> 20;  // uniform per block
    const float* sw = (w == 0) ? wq : (w == 1) ? wk : (w == 2) ? wv : wo;
    src = sw + (j & 1048575);
  }
  float4 f = *(const float4*)src;
  bf16x4 o = {f2bf(f.x), f2bf(f.y), f2bf(f.z), f2bf(f.w)};
  *(bf16x4*)(dst + idx) = o;
}

// ---------------- QKV projection GEMM + RoPE epilogue ---------------------
// R16: BK=32, double-buffered LDS (2 x 16KB = 32KB -> occupancy unchanged,
// 3 blocks/CU), ONE barrier per k-step with stage(t+1) issued BEFORE the
// ds_read+MFMA of tile t -> DMA overlaps compute; barrier drain only catches
// stragglers (T3-minimum recipe; attacks the R15 counters' stall: MfmaUtil
// 12% with FETCH/WRITE both near-ideal). 64B rows need a 2-bit XOR granule
// swizzle g^=(row&3)^((row>>2)&3): pre-swizzled global source + linear
// gl_lds dest + swizzled read = conflict-free (2 lanes/bank).
// XCD mapping kept from R15 (FETCH 80.7->32.3 MB verified).
__global__ __launch_bounds__(256) void gemm_qkv_kernel(
    const bf16* __restrict__ xb, const bf16* __restrict__ wb,
    const float* __restrict__ tab,
    bf16* __restrict__ Qb, bf16* __restrict__ Kb, bf16* __restrict__ Vtb) {
  __shared__ __align__(16) bf16 smem[16384];  // A0|B0|A1|B1 (4096 each); epi T
  int tid = threadIdx.x;
  int lane = tid & 63, w = tid >> 6;
  int l15 = lane & 15, quad = lane >> 4;
  int bid = blockIdx.x;
  int xcd = bid & 7, j = bid >> 3;       // XCD round-robin; j in [0,96)
  int by = (xcd & 3) * 8 + (j & 7);      // 32 M-tiles, 8 per XCD row-group
  int bx = (xcd >> 2) * 12 + (j >> 3);   // 24 N-tiles, 12 per XCD col-group
  int mb = by * 128, nb = bx * 128;
  int mq = (w & 1) * 64, nq = (w >> 1) * 64;
  int rq = lane >> 2;                               // row-in-16 for staging
  int gsrc = (lane & 3) ^ (rq & 3) ^ (lane >> 4);   // pre-swizzled src granule
  const bf16* agp0 = xb + (size_t)(mb + w * 32 + rq) * 1024 + gsrc * 8;
  const bf16* agp1 = agp0 + 16 * 1024;
  const bf16* bgp0 = wb + (size_t)(nb + w * 32 + rq) * 1024 + gsrc * 8;
  const bf16* bgp1 = bgp0 + 16 * 1024;
  f32x4 acc[4][4];
#pragma unroll
  for (int i = 0; i < 4; ++i)
#pragma unroll
    for (int j2 = 0; j2 < 4; ++j2)
      for (int r = 0; r < 4; ++r) acc[i][j2][r] = 0.f;
  // prologue: stage k-step 0 into buffer 0
  gl_lds16(agp0, smem + w * 1024);
  gl_lds16(agp1, smem + w * 1024 + 512);
  gl_lds16(bgp0, smem + 4096 + w * 1024);
  gl_lds16(bgp1, smem + 4096 + w * 1024 + 512);
  agp0 += 32; agp1 += 32; bgp0 += 32; bgp1 += 32;
  __syncthreads();
  int rg = quad ^ (l15 & 3) ^ (l15 >> 2);  // read granule (conflict-free)
  for (int kt = 0; kt < 32; ++kt) {
    bf16* Ab = smem + (kt & 1) * 8192;
    bf16* Bb = Ab + 4096;
    if (kt < 31) {  // stage k-step kt+1 into the other buffer (overlaps MFMA)
      bf16* An = smem + ((kt & 1) ^ 1) * 8192;
      bf16* Bn = An + 4096;
      gl_lds16(agp0, An + w * 1024);
      gl_lds16(agp1, An + w * 1024 + 512);
      gl_lds16(bgp0, Bn + w * 1024);
      gl_lds16(bgp1, Bn + w * 1024 + 512);
      agp0 += 32; agp1 += 32; bgp0 += 32; bgp1 += 32;
    }
    bf16x8 af[4], bfr[4];
#pragma unroll
    for (int mt = 0; mt < 4; ++mt)
      af[mt] = *(const bf16x8*)(Ab + (mq + mt * 16 + l15) * 32 + rg * 8);
#pragma unroll
    for (int nt = 0; nt < 4; ++nt)
      bfr[nt] = *(const bf16x8*)(Bb + (nq + nt * 16 + l15) * 32 + rg * 8);
#pragma unroll
    for (int mt = 0; mt < 4; ++mt)
#pragma unroll
      for (int nt = 0; nt < 4; ++nt)
        acc[mt][nt] = __builtin_amdgcn_mfma_f32_16x16x32_bf16(af[mt], bfr[nt], acc[mt][nt], 0, 0, 0);
    __syncthreads();
  }
  int b = mb >> 11;        // block-uniform batch
  int mtok = mb & 2047;    // block-uniform token base
  if (bx < 16) {
    // ---- Q or K tile: RoPE epilogue (C col=l15 -> e, row=quad*4+r -> tok)
    bf16* dst = (bx < 8) ? Qb : Kb;
#pragma unroll
    for (int nt = 0; nt < 4; ++nt) {
      int e = nb + nq + nt * 16 + l15;
      int d = e & 63;
      int h = (e & 1023) >> 6;
      int tbase = d & ~1;
#pragma unroll
      for (int mt = 0; mt < 4; ++mt) {
#pragma unroll
        for (int r = 0; r < 4; ++r) {
          int ltok = mtok + mq + mt * 16 + quad * 4 + r;
          float val = acc[mt][nt][r];
          float p = __shfl_xor(val, 1);
          float2 cs2 = *(const float2*)(tab + ltok * 64 + tbase);
          float outv = (e & 1) ? (p * cs2.y + val * cs2.x) : (val * cs2.x - p * cs2.y);
          dst[(size_t)(((b << 4) + h) * 2048 + ltok) * 64 + d] = f2bf(outv);
        }
      }
    }
  } else {
    // ---- V tile: transpose via LDS (smem dead after K-loop), coalesced Vt
    bf16* T = smem;  // [64][136] bf16 = 17408 B
    for (int h2 = 0; h2 < 2; ++h2) {
      if ((w >> 1) == h2) {  // waves owning cols [h2*64, h2*64+64)
#pragma unroll
        for (int nt = 0; nt < 4; ++nt)
#pragma unroll
          for (int mt = 0; mt < 4; ++mt) {
            bf16x4 tv = {f2bf(acc[mt][nt][0]), f2bf(acc[mt][nt][1]),
                         f2bf(acc[mt][nt][2]), f2bf(acc[mt][nt][3])};
            *(bf16x4*)&T[(nt * 16 + l15) * 136 + mq + mt * 16 + quad * 4] = tv;
          }
      }
      __syncthreads();
      int row = tid >> 2, cs = (tid & 3) * 32;
      int e = nb + h2 * 64 + row;
      int d = e & 63, hh = (e & 1023) >> 6;
      bf16* vdst = Vtb + ((size_t)((b << 4) + hh) * 64 + d) * 2048 + mtok + cs;
#pragma unroll
      for (int j3 = 0; j3 < 4; ++j3)
        *(bf16x8*)(vdst + j3 * 8) = *(const bf16x8*)&T[row * 136 + cs + j3 * 8];
      __syncthreads();
    }
  }
}

// ---------------- causal flash attention v11 (T14 async-STAGE) -------------
// R16: replace per-tile gl_lds staging (whose vmcnt(0) drain serialized DMA
// before compute) with reg-staged prefetch: issue 4 plain 16B loads for tile
// t+1 at tile start (+16 VGPR), consume (ds_write into Ks/Vs) after the
// compute barrier. L2 latency hides under QK+softmax+PV. LDS unchanged
// (25KB -> 6 blocks/CU). Dead always-true kb<=qmax guard removed.
#define SCALE_L2E 0.18033688f  // 0.125 * log2(e)
__global__ __launch_bounds__(256) void attn_kernel(
    const bf16* __restrict__ Qb, const bf16* __restrict__ Kb,
    const bf16* __restrict__ Vtb, bf16* __restrict__ Ob) {
  __shared__ __align__(16) bf16 Ks[64 * 64];
  __shared__ __align__(16) bf16 Vs[64 * 64];
  __shared__ __align__(16) bf16 pbuf[4][16 * 72];
  int tid = threadIdx.x;
  int lane = tid & 63, w = tid >> 6;
  int l15 = lane & 15, quad = lane >> 4;
  int bidx = blockIdx.x;
  int bh = bidx & 31;
  int qt = 31 - (bidx >> 5);  // LPT: longest q-tiles dispatch first
  int qbase = qt * 64;
  const bf16* Qp = Qb + (size_t)bh * 131072;
  const bf16* Kp = Kb + (size_t)bh * 131072;
  const bf16* Vp = Vtb + (size_t)bh * 131072;
  int r8 = lane >> 3;
  int gsw8 = (lane & 7) ^ r8;       // staging source granule swizzle
  int g0 = quad ^ (l15 & 7);        // read granule, k-chunk 0
  int g1 = (4 + quad) ^ (l15 & 7);  // read granule, k-chunk 1
  bf16x8 qf[2];
#pragma unroll
  for (int c = 0; c < 2; ++c)
    qf[c] = *(const bf16x8*)(Qp + (size_t)(qbase + w * 16 + l15) * 64 + c * 32 + quad * 8);
  f32x4 oacc[4];
#pragma unroll
  for (int dt = 0; dt < 4; ++dt)
    for (int r = 0; r < 4; ++r) oacc[dt][r] = 0.f;
  float lpart = 0.f;  // per-lane partial denominator
  int qmin_w = qbase + w * 16;
  int ntiles = qt + 1;

  {  // prologue: stage tile 0 via gl_lds
    const bf16* ksrc = Kp + (size_t)(w * 16 + r8) * 64 + gsw8 * 8;
    bf16* kdst = &Ks[(w * 16) * 64];
    gl_lds16(ksrc, kdst);
    gl_lds16(ksrc + 8 * 64, kdst + 8 * 64);
    const bf16* vsrc = Vp + (size_t)(w * 16 + r8) * 2048 + gsw8 * 8;
    bf16* vdst = &Vs[(w * 16) * 64];
    gl_lds16(vsrc, vdst);
    gl_lds16(vsrc + 8 * 2048, vdst + 8 * 64);
  }
  __syncthreads();

  for (int t = 0; t < ntiles; ++t) {
    int kb = t * 64;
    bool pf = (t + 1 < ntiles);  // wave-uniform
    bf16x8 rk0, rk1, rv0, rv1;
    if (pf) {  // issue prefetch for tile t+1; lands during compute below
      const bf16* ksrc = Kp + (size_t)(kb + 64 + w * 16 + r8) * 64 + gsw8 * 8;
      rk0 = *(const bf16x8*)ksrc;
      rk1 = *(const bf16x8*)(ksrc + 8 * 64);
      const bf16* vsrc = Vp + (size_t)(w * 16 + r8) * 2048 + kb + 64 + gsw8 * 8;
      rv0 = *(const bf16x8*)vsrc;
      rv1 = *(const bf16x8*)(vsrc + 8 * 2048);
    }
    {  // compute tile t
      bf16x8 kf[4][2], vf[4][2];
#pragma unroll
      for (int kt = 0; kt < 4; ++kt) {
        kf[kt][0] = *(const bf16x8*)(&Ks[(kt * 16 + l15) * 64 + g0 * 8]);
        kf[kt][1] = *(const bf16x8*)(&Ks[(kt * 16 + l15) * 64 + g1 * 8]);
      }
#pragma unroll
      for (int dt = 0; dt < 4; ++dt) {
        vf[dt][0] = *(const bf16x8*)(&Vs[(dt * 16 + l15) * 64 + g0 * 8]);
        vf[dt][1] = *(const bf16x8*)(&Vs[(dt * 16 + l15) * 64 + g1 * 8]);
      }
      int q = qmin_w + l15;
      f32x4 s[4];
#pragma unroll
      for (int kt = 0; kt < 4; ++kt) {
        for (int r = 0; r < 4; ++r) s[kt][r] = 0.f;
        s[kt] = __builtin_amdgcn_mfma_f32_16x16x32_bf16(kf[kt][0], qf[0], s[kt], 0, 0, 0);
        s[kt] = __builtin_amdgcn_mfma_f32_16x16x32_bf16(kf[kt][1], qf[1], s[kt], 0, 0, 0);
      }
      float pe[16];
      if (kb + 63 > qmin_w) {  // diagonal: per-element mask (wave-uniform test)
#pragma unroll
        for (int kt = 0; kt < 4; ++kt)
#pragma unroll
          for (int r = 0; r < 4; ++r) {
            int key = kb + kt * 16 + quad * 4 + r;
            pe[kt * 4 + r] = (key <= q) ? exp2f(s[kt][r] * SCALE_L2E) : 0.f;
          }
      } else {
#pragma unroll
        for (int kt = 0; kt < 4; ++kt)
#pragma unroll
          for (int r = 0; r < 4; ++r) pe[kt * 4 + r] = exp2f(s[kt][r] * SCALE_L2E);
      }
#pragma unroll
      for (int i = 0; i < 16; ++i) lpart += pe[i];
#pragma unroll
      for (int kt = 0; kt < 4; ++kt) {
        bf16x4 pw = {f2bf(pe[kt * 4]), f2bf(pe[kt * 4 + 1]), f2bf(pe[kt * 4 + 2]), f2bf(pe[kt * 4 + 3])};
        *(bf16x4*)&pbuf[w][l15 * 72 + kt * 16 + quad * 4] = pw;
      }
      // same-wave LDS round-trip: lgkmcnt ordering only, no barrier
      bf16x8 pb0 = *(const bf16x8*)&pbuf[w][l15 * 72 + quad * 8];
      bf16x8 pb1 = *(const bf16x8*)&pbuf[w][l15 * 72 + 32 + quad * 8];
#pragma unroll
      for (int dt = 0; dt < 4; ++dt) {
        oacc[dt] = __builtin_amdgcn_mfma_f32_16x16x32_bf16(vf[dt][0], pb0, oacc[dt], 0, 0, 0);
        oacc[dt] = __builtin_amdgcn_mfma_f32_16x16x32_bf16(vf[dt][1], pb1, oacc[dt], 0, 0, 0);
      }
    }
    __syncthreads();  // all reads of Ks/Vs done
    if (pf) {  // write prefetched tile t+1 into LDS (vmcnt drained by compiler)
      bf16* kd = &Ks[(w * 16) * 64] + lane * 8;
      *(bf16x8*)kd = rk0;
      *(bf16x8*)(kd + 512) = rk1;
      bf16* vd = &Vs[(w * 16) * 64] + lane * 8;
      *(bf16x8*)vd = rv0;
      *(bf16x8*)(vd + 512) = rv1;
    }
    __syncthreads();  // writes visible before next tile's reads
  }
  float lrun = lpart;
  lrun += __shfl_xor(lrun, 16);
  lrun += __shfl_xor(lrun, 32);
  int b0 = bh >> 4, h = bh & 15;
  float inv = 1.f / lrun;
  int q = qmin_w + l15;
  bf16* obase = Ob + ((size_t)(b0 * 2048 + q)) * 1024 + h * 64;
#pragma unroll
  for (int dt = 0; dt < 4; ++dt)
#pragma unroll
    for (int r = 0; r < 4; ++r)
      obase[dt * 16 + quad * 4 + r] = f2bf(oacc[dt][r] * inv);
}

// ---------------- output projection GEMM (R15, frozen) ---------------------
__global__ __launch_bounds__(256) void gemm_out_kernel(
    const bf16* __restrict__ Ob, const bf16* __restrict__ wob,
    float* __restrict__ out) {
  __shared__ __align__(16) bf16 As[128 * 64];
  __shared__ __align__(16) bf16 Bs[64 * 64];
  int tid = threadIdx.x;
  int lane = tid & 63, w = tid >> 6;
  int l15 = lane & 15, quad = lane >> 4;
  int bid = blockIdx.x;
  int xcd = bid & 7, j = bid >> 3;       // j in [0,64)
  int by = (xcd & 3) * 8 + (j & 7);      // 32 M-tiles
  int bx = (xcd >> 2) * 8 + (j >> 3);    // 16 N-tiles
  int mb = by * 128, nb = bx * 64;
  int mq = (w & 1) * 64, nq = (w >> 1) * 32;
  int gsw = (lane & 7) ^ ((lane >> 3) & 7);
  const bf16* agp = Ob + (size_t)(mb + w * 32 + (lane >> 3)) * 1024 + gsw * 8;
  const bf16* bgp = wob + (size_t)(nb + w * 16 + (lane >> 3)) * 1024 + gsw * 8;
  bf16* alp = As + (w * 32) * 64;
  bf16* blp = Bs + (w * 16) * 64;
  f32x4 acc[4][2];
#pragma unroll
  for (int i = 0; i < 4; ++i)
#pragma unroll
    for (int j2 = 0; j2 < 2; ++j2)
      for (int r = 0; r < 4; ++r) acc[i][j2][r] = 0.f;
  for (int kt = 0; kt < 16; ++kt) {
#pragma unroll
    for (int i = 0; i < 4; ++i)
      gl_lds16(agp + i * 8192, alp + i * 512);  // i*8 rows of A
#pragma unroll
    for (int i = 0; i < 2; ++i)
      gl_lds16(bgp + i * 8192, blp + i * 512);  // i*8 rows of B
    agp += 64; bgp += 64;
    __syncthreads();
#pragma unroll
    for (int c = 0; c < 2; ++c) {
      bf16x8 af[4], bfr[2];
      int rg = (c * 4 + quad);
#pragma unroll
      for (int mt = 0; mt < 4; ++mt)
        af[mt] = *(const bf16x8*)(As + (mq + mt * 16 + l15) * 64 + (rg ^ (l15 & 7)) * 8);
#pragma unroll
      for (int nt = 0; nt < 2; ++nt)
        bfr[nt] = *(const bf16x8*)(Bs + (nq + nt * 16 + l15) * 64 + (rg ^ (l15 & 7)) * 8);
#pragma unroll
      for (int mt = 0; mt < 4; ++mt)
#pragma unroll
        for (int nt = 0; nt < 2; ++nt)
          acc[mt][nt] = __builtin_amdgcn_mfma_f32_16x16x32_bf16(af[mt], bfr[nt], acc[mt][nt], 0, 0, 0);
    }
    __syncthreads();
  }
#pragma unroll
  for (int mt = 0; mt < 4; ++mt)
#pragma unroll
    for (int nt = 0; nt < 2; ++nt)
#pragma unroll
      for (int r = 0; r < 4; ++r)
        out[(size_t)(mb + mq + mt * 16 + quad * 4 + r) * 1024 + nb + nq + nt * 16 + l15] = acc[mt][nt][r];
}

extern "C" void kernel_launch(void* const* d_in, const int* in_sizes, int n_in,
                              void* d_out, int out_size, void* d_ws, size_t ws_size,
                              hipStream_t stream) {
  const float* x  = (const float*)d_in[0];
  const float* wq = (const float*)d_in[1];
  const float* wk = (const float*)d_in[2];
  const float* wv = (const float*)d_in[3];
  const float* wo = (const float*)d_in[4];
  const int* pos  = (const int*)d_in[5];
  float* out = (float*)d_out;
  // ws layout (bf16 elems): xb[4M] | wb[4x1M] | Q[4M] | K[4M] | Vt[4M] | O[4M]
  bf16* wsb = (bf16*)d_ws;
  bf16* xb  = wsb;
  bf16* wb  = wsb + 4194304;
  bf16* Qb  = wsb + 8388608;
  bf16* Kb  = wsb + 12582912;
  bf16* Vtb = wsb + 16777216;
  bf16* Obf = wsb + 20971520;
  float* tab = (float*)Obf;  // 512 KB table, dead before attn writes Obf
  hipLaunchKernelGGL(cvt_kernel, dim3(8448), dim3(256), 0, stream, x, wq, wk, wv, wo, wsb, pos, tab);
  hipLaunchKernelGGL(gemm_qkv_kernel, dim3(768), dim3(256), 0, stream, xb, wb, tab, Qb, Kb, Vtb);
  hipLaunchKernelGGL(attn_kernel, dim3(1024), dim3(256), 0, stream, Qb, Kb, Vtb, Obf);
  hipLaunchKernelGGL(gemm_out_kernel, dim3(512), dim3(256), 0, stream, Obf, wb + 3 * 1048576, out);
}